// Round 1
// baseline (315.809 us; speedup 1.0000x reference)
//
#include <hip/hip_runtime.h>

#define BB 16
#define CC 256
#define HWN 3136
#define NCG 64
#define NCI 32
#define NPP 784   // 28*28

// ---------------- kernel 0: zero bn2 accumulators ----------------
__global__ void k_zero(float* __restrict__ p) {
    p[threadIdx.x] = 0.0f;  // 128 floats
}

// ---------------- kernel 1: BN1 stats -> affine coeffs ----------------
// one block per channel; ab[c]=a, ab[256+c]=b so that bn(x)=a*x+b
__global__ __launch_bounds__(256) void k_bn1(const float* __restrict__ x,
                                             const float* __restrict__ gamma,
                                             const float* __restrict__ beta,
                                             float* __restrict__ ab) {
    int c = blockIdx.x;
    int tid = threadIdx.x;
    float s = 0.f, q = 0.f;
    for (int b = 0; b < BB; ++b) {
        const float* p = x + ((size_t)(b * CC + c)) * HWN;
        for (int i = tid; i < HWN; i += 256) {
            float v = p[i];
            s += v;
            q += v * v;
        }
    }
    __shared__ float sh[512];
    sh[tid] = s; sh[256 + tid] = q;
    __syncthreads();
    for (int off = 128; off > 0; off >>= 1) {
        if (tid < off) { sh[tid] += sh[tid + off]; sh[256 + tid] += sh[256 + tid + off]; }
        __syncthreads();
    }
    if (tid == 0) {
        const float inv = 1.0f / (BB * HWN);
        float mean = sh[0] * inv;
        float var  = sh[256] * inv - mean * mean;
        float a = gamma[c] * rsqrtf(var + 1e-5f);
        ab[c] = a;
        ab[CC + c] = beta[c] - mean * a;
    }
}

// ---------------- kernel 2: fused BN1+ReLU+conv1x1 (theta|phi|g) ----------------
// grid (49, B); block 256; tile: 128 out-ch x 64 hw; K=256 in chunks of 16
__global__ __launch_bounds__(256) void k_conv1(const float* __restrict__ x,
                                               const float* __restrict__ ab,
                                               const float* __restrict__ w_g,  const float* __restrict__ b_g,
                                               const float* __restrict__ w_t,  const float* __restrict__ b_t,
                                               const float* __restrict__ w_p,  const float* __restrict__ b_p,
                                               float* __restrict__ conv1) {
    int b = blockIdx.y;
    int hw0 = blockIdx.x * 64;
    int tid = threadIdx.x;
    int tx = tid & 15;        // hw group (4 each)
    int ty = tid >> 4;        // out-ch group (8 each)

    __shared__ float wl[128 * 17];   // [o][k], stride 17 (conflict-free)
    __shared__ float xl[16 * 64];    // [k][hw]

    float acc[8][4];
    #pragma unroll
    for (int j = 0; j < 8; ++j)
        for (int u = 0; u < 4; ++u) acc[j][u] = 0.f;

    for (int k0 = 0; k0 < CC; k0 += 16) {
        #pragma unroll
        for (int i = 0; i < 8; ++i) {
            int e = tid + i * 256;       // 2048
            int o = e >> 4, k = e & 15;
            const float* wp = (o < 32) ? (w_t + o * CC)
                             : (o < 64) ? (w_p + (o - 32) * CC)
                                        : (w_g + (o - 64) * CC);
            wl[o * 17 + k] = wp[k0 + k];
        }
        #pragma unroll
        for (int i = 0; i < 4; ++i) {
            int e = tid + i * 256;       // 1024
            int k = e >> 6, hw = e & 63;
            int c = k0 + k;
            float v = x[((size_t)(b * CC + c)) * HWN + hw0 + hw];
            xl[k * 64 + hw] = fmaxf(fmaf(ab[c], v, ab[CC + c]), 0.f);
        }
        __syncthreads();
        #pragma unroll
        for (int k = 0; k < 16; ++k) {
            float4 xv = *(const float4*)&xl[k * 64 + tx * 4];
            #pragma unroll
            for (int j = 0; j < 8; ++j) {
                float wv = wl[(ty * 8 + j) * 17 + k];
                acc[j][0] = fmaf(wv, xv.x, acc[j][0]);
                acc[j][1] = fmaf(wv, xv.y, acc[j][1]);
                acc[j][2] = fmaf(wv, xv.z, acc[j][2]);
                acc[j][3] = fmaf(wv, xv.w, acc[j][3]);
            }
        }
        __syncthreads();
    }
    #pragma unroll
    for (int j = 0; j < 8; ++j) {
        int o = ty * 8 + j;
        float bias = (o < 32) ? b_t[o] : (o < 64) ? b_p[o - 32] : b_g[o - 64];
        float4 r = make_float4(acc[j][0] + bias, acc[j][1] + bias,
                               acc[j][2] + bias, acc[j][3] + bias);
        *(float4*)&conv1[((size_t)(b * 128 + o)) * HWN + hw0 + tx * 4] = r;
    }
}

// ---------------- kernel 3: fused maxpool + partial S = phi_p . g_p^T ----------------
// grid (14, B): m-chunks of 56 pooled positions; block 256
// conv1 channels: [0,32)=theta, [32,64)=phi, [64,128)=g
__global__ __launch_bounds__(256) void k_spart(const float* __restrict__ conv1,
                                               float* __restrict__ spart) {
    int cx = blockIdx.x;   // 0..13
    int b  = blockIdx.y;
    int tid = threadIdx.x;
    __shared__ float pl[96 * 60];   // rows: 0..31 phi_p, 32..95 g_p; stride 60

    #pragma unroll
    for (int i = 0; i < 21; ++i) {
        int e = tid + i * 256;            // 5376 = 96*56
        int ch = e / 56, mm = e - ch * 56;
        int m = cx * 56 + mm;
        int mh = m / 28, mw = m - mh * 28;
        const float* p = conv1 + ((size_t)(b * 128 + 32 + ch)) * HWN + mh * 112 + mw * 2;
        pl[ch * 60 + mm] = fmaxf(fmaxf(p[0], p[1]), fmaxf(p[56], p[57]));
    }
    __syncthreads();

    int cg = tid & 63;
    int cib = tid >> 6;    // 0..3
    float acc[8];
    #pragma unroll
    for (int i = 0; i < 8; ++i) acc[i] = 0.f;
    const float* pb = &pl[(32 + cg) * 60];
    for (int mm4 = 0; mm4 < 14; ++mm4) {
        float4 bv = *(const float4*)&pb[mm4 * 4];
        #pragma unroll
        for (int i = 0; i < 8; ++i) {
            float4 av = *(const float4*)&pl[(cib + 4 * i) * 60 + mm4 * 4];
            acc[i] = fmaf(av.x, bv.x, acc[i]);
            acc[i] = fmaf(av.y, bv.y, acc[i]);
            acc[i] = fmaf(av.z, bv.z, acc[i]);
            acc[i] = fmaf(av.w, bv.w, acc[i]);
        }
    }
    float* out = spart + ((size_t)(b * 14 + cx)) * 2048;
    #pragma unroll
    for (int i = 0; i < 8; ++i) out[tid + i * 256] = acc[i];
}

// ---------------- kernel 4: y = theta^T S / Np + BN2 partial stats ----------------
// grid (7, B); block 448; each thread: 4 hw x 16 cg
__global__ __launch_bounds__(448) void k_y(const float* __restrict__ conv1,
                                           const float* __restrict__ spart,
                                           float* __restrict__ y,
                                           float* __restrict__ bn2acc) {
    int bx = blockIdx.x;
    int b  = blockIdx.y;
    int tid = threadIdx.x;
    __shared__ float S[2048];       // [ci][cg]
    __shared__ float shs[64], shq[64];

    for (int id = tid; id < 2048; id += 448) {
        const float* p = spart + (size_t)b * 14 * 2048 + id;
        float s = 0.f;
        #pragma unroll
        for (int j = 0; j < 14; ++j) s += p[j * 2048];
        S[id] = s * (1.0f / NPP);
    }
    if (tid < 64) { shs[tid] = 0.f; shq[tid] = 0.f; }
    __syncthreads();

    int lm  = tid % 112;
    int cgb = (tid / 112) * 16;
    int hw4 = bx * 448 + lm * 4;

    float4 acc[16];
    #pragma unroll
    for (int j = 0; j < 16; ++j) acc[j] = make_float4(0.f, 0.f, 0.f, 0.f);

    const float* th = conv1 + (size_t)b * 128 * HWN + hw4;
    for (int ci = 0; ci < NCI; ++ci) {
        float4 t = *(const float4*)(th + (size_t)ci * HWN);
        const float* sp = &S[ci * 64 + cgb];
        #pragma unroll
        for (int j = 0; j < 16; ++j) {
            float sv = sp[j];
            acc[j].x = fmaf(t.x, sv, acc[j].x);
            acc[j].y = fmaf(t.y, sv, acc[j].y);
            acc[j].z = fmaf(t.z, sv, acc[j].z);
            acc[j].w = fmaf(t.w, sv, acc[j].w);
        }
    }
    #pragma unroll
    for (int j = 0; j < 16; ++j) {
        int cg = cgb + j;
        *(float4*)&y[((size_t)(b * NCG + cg)) * HWN + hw4] = acc[j];
        float s = acc[j].x + acc[j].y + acc[j].z + acc[j].w;
        float q = acc[j].x * acc[j].x + acc[j].y * acc[j].y +
                  acc[j].z * acc[j].z + acc[j].w * acc[j].w;
        atomicAdd(&shs[cg], s);
        atomicAdd(&shq[cg], q);
    }
    __syncthreads();
    if (tid < 64) {
        atomicAdd(&bn2acc[tid], shs[tid]);
        atomicAdd(&bn2acc[64 + tid], shq[tid]);
    }
}

// ---------------- kernel 5: BN2 finalize ----------------
__global__ void k_bn2fin(const float* __restrict__ bn2acc,
                         const float* __restrict__ gamma,
                         const float* __restrict__ beta,
                         float* __restrict__ ab2) {
    int c = threadIdx.x;   // 64
    const float inv = 1.0f / (BB * HWN);
    float mean = bn2acc[c] * inv;
    float var  = bn2acc[64 + c] * inv - mean * mean;
    float a = gamma[c] * rsqrtf(var + 1e-5f);
    ab2[c] = a;
    ab2[64 + c] = beta[c] - mean * a;
}

// ---------------- kernel 6: BN2+ReLU+conv1x1(z) + residual ----------------
// grid (49, B, 2); block 256; tile 128 co x 64 hw; K=64 (full)
__global__ __launch_bounds__(256) void k_convz(const float* __restrict__ y,
                                               const float* __restrict__ ab2,
                                               const float* __restrict__ w_z,
                                               const float* __restrict__ b_z,
                                               const float* __restrict__ x,
                                               float* __restrict__ out) {
    int b = blockIdx.y;
    int hw0 = blockIdx.x * 64;
    int coh = blockIdx.z * 128;
    int tid = threadIdx.x;
    int tx = tid & 15;
    int ty = tid >> 4;

    __shared__ float wl[128 * 65];   // [co][k], stride 65
    __shared__ float yl[64 * 64];    // [k][hw]

    #pragma unroll
    for (int i = 0; i < 32; ++i) {
        int e = tid + i * 256;   // 8192
        int co = e >> 6, k = e & 63;
        wl[co * 65 + k] = w_z[(coh + co) * 64 + k];
    }
    #pragma unroll
    for (int i = 0; i < 16; ++i) {
        int e = tid + i * 256;   // 4096
        int k = e >> 6, hw = e & 63;
        float v = y[((size_t)(b * NCG + k)) * HWN + hw0 + hw];
        yl[k * 64 + hw] = fmaxf(fmaf(ab2[k], v, ab2[64 + k]), 0.f);
    }
    __syncthreads();

    float acc[8][4];
    #pragma unroll
    for (int j = 0; j < 8; ++j)
        for (int u = 0; u < 4; ++u) acc[j][u] = 0.f;

    #pragma unroll
    for (int k = 0; k < 64; ++k) {
        float4 yv = *(const float4*)&yl[k * 64 + tx * 4];
        #pragma unroll
        for (int j = 0; j < 8; ++j) {
            float wv = wl[(ty * 8 + j) * 65 + k];
            acc[j][0] = fmaf(wv, yv.x, acc[j][0]);
            acc[j][1] = fmaf(wv, yv.y, acc[j][1]);
            acc[j][2] = fmaf(wv, yv.z, acc[j][2]);
            acc[j][3] = fmaf(wv, yv.w, acc[j][3]);
        }
    }
    #pragma unroll
    for (int j = 0; j < 8; ++j) {
        int co = coh + ty * 8 + j;
        size_t base = ((size_t)(b * CC + co)) * HWN + hw0 + tx * 4;
        float4 xv = *(const float4*)&x[base];
        float bz = b_z[co];
        float4 r = make_float4(acc[j][0] + bz + xv.x, acc[j][1] + bz + xv.y,
                               acc[j][2] + bz + xv.z, acc[j][3] + bz + xv.w);
        *(float4*)&out[base] = r;
    }
}

extern "C" void kernel_launch(void* const* d_in, const int* in_sizes, int n_in,
                              void* d_out, int out_size, void* d_ws, size_t ws_size,
                              hipStream_t stream) {
    (void)in_sizes; (void)n_in; (void)out_size; (void)ws_size;
    const float* x   = (const float*)d_in[0];
    const float* g1  = (const float*)d_in[1];
    const float* b1  = (const float*)d_in[2];
    const float* w_g = (const float*)d_in[3];
    const float* b_g = (const float*)d_in[4];
    const float* w_t = (const float*)d_in[5];
    const float* b_t = (const float*)d_in[6];
    const float* w_p = (const float*)d_in[7];
    const float* b_p = (const float*)d_in[8];
    const float* g2  = (const float*)d_in[9];
    const float* b2  = (const float*)d_in[10];
    const float* w_z = (const float*)d_in[11];
    const float* b_z = (const float*)d_in[12];
    float* out = (float*)d_out;

    float* ws     = (float*)d_ws;
    float* ab1    = ws;                                  // 512
    float* bn2acc = ws + 512;                            // 128
    float* ab2    = ws + 640;                            // 128
    float* conv1  = ws + 1024;                           // 16*128*3136
    float* spart  = conv1 + (size_t)BB * 128 * HWN;      // 16*14*2048
    float* yb     = spart + (size_t)BB * 14 * 2048;      // 16*64*3136

    k_zero  <<<dim3(1),        dim3(128), 0, stream>>>(bn2acc);
    k_bn1   <<<dim3(CC),       dim3(256), 0, stream>>>(x, g1, b1, ab1);
    k_conv1 <<<dim3(49, BB),   dim3(256), 0, stream>>>(x, ab1, w_g, b_g, w_t, b_t, w_p, b_p, conv1);
    k_spart <<<dim3(14, BB),   dim3(256), 0, stream>>>(conv1, spart);
    k_y     <<<dim3(7, BB),    dim3(448), 0, stream>>>(conv1, spart, yb, bn2acc);
    k_bn2fin<<<dim3(1),        dim3(64),  0, stream>>>(bn2acc, g2, b2, ab2);
    k_convz <<<dim3(49, BB, 2),dim3(256), 0, stream>>>(yb, ab2, w_z, b_z, x, out);
}

// Round 2
// 263.524 us; speedup vs baseline: 1.1984x; 1.1984x over previous
//
#include <hip/hip_runtime.h>

#define BB 16
#define CC 256
#define HWN 3136
#define NCG 64
#define NCI 32
#define NPP 784   // 28*28

// ---------------- kernel 0: zero bn1/bn2 accumulators ----------------
__global__ __launch_bounds__(256) void k_zero(float* __restrict__ p) {
    for (int i = threadIdx.x; i < 640; i += 256) p[i] = 0.0f;
}

// ---------------- kernel 1: BN1 partial sums (one block per (b,c)) ----------------
// acc[c] += sum, acc[256+c] += sumsq
__global__ __launch_bounds__(256) void k_bn1a(const float* __restrict__ x,
                                              float* __restrict__ acc) {
    int blk = blockIdx.x;           // b*CC + c
    int c = blk & (CC - 1);
    const float4* p = (const float4*)(x + (size_t)blk * HWN);
    int tid = threadIdx.x;
    float s = 0.f, q = 0.f;
    #pragma unroll
    for (int i = tid; i < 784; i += 256) {
        float4 v = p[i];
        s += v.x + v.y + v.z + v.w;
        q += v.x * v.x + v.y * v.y + v.z * v.z + v.w * v.w;
    }
    #pragma unroll
    for (int off = 32; off > 0; off >>= 1) {
        s += __shfl_down(s, off);
        q += __shfl_down(q, off);
    }
    __shared__ float sh[8];
    int wid = tid >> 6, lane = tid & 63;
    if (lane == 0) { sh[wid] = s; sh[4 + wid] = q; }
    __syncthreads();
    if (tid == 0) {
        atomicAdd(&acc[c], sh[0] + sh[1] + sh[2] + sh[3]);
        atomicAdd(&acc[CC + c], sh[4] + sh[5] + sh[6] + sh[7]);
    }
}

// ---------------- kernel 2: fused BN1+ReLU+conv1x1 (theta|phi|g) ----------------
// grid (49, B); block 256; tile: 128 out-ch x 64 hw; K=256 in chunks of 16
__global__ __launch_bounds__(256) void k_conv1(const float* __restrict__ x,
                                               const float* __restrict__ bn1acc,
                                               const float* __restrict__ gamma,
                                               const float* __restrict__ beta,
                                               const float* __restrict__ w_g,  const float* __restrict__ b_g,
                                               const float* __restrict__ w_t,  const float* __restrict__ b_t,
                                               const float* __restrict__ w_p,  const float* __restrict__ b_p,
                                               float* __restrict__ conv1) {
    int b = blockIdx.y;
    int hw0 = blockIdx.x * 64;
    int tid = threadIdx.x;
    int tx = tid & 15;        // hw group (4 each)
    int ty = tid >> 4;        // out-ch group (8 each)

    __shared__ float ab_s[512];      // a then b per channel
    __shared__ float wl[128 * 17];   // [o][k], stride 17 (conflict-free)
    __shared__ float xl[16 * 64];    // [k][hw]

    {   // fold BN1 finalize in: per-channel affine coeffs
        const float inv = 1.0f / (BB * HWN);
        float mean = bn1acc[tid] * inv;
        float var  = bn1acc[CC + tid] * inv - mean * mean;
        float a = gamma[tid] * rsqrtf(var + 1e-5f);
        ab_s[tid] = a;
        ab_s[CC + tid] = beta[tid] - mean * a;
    }
    __syncthreads();

    float acc[8][4];
    #pragma unroll
    for (int j = 0; j < 8; ++j)
        for (int u = 0; u < 4; ++u) acc[j][u] = 0.f;

    for (int k0 = 0; k0 < CC; k0 += 16) {
        #pragma unroll
        for (int i = 0; i < 8; ++i) {
            int e = tid + i * 256;       // 2048
            int o = e >> 4, k = e & 15;
            const float* wp = (o < 32) ? (w_t + o * CC)
                             : (o < 64) ? (w_p + (o - 32) * CC)
                                        : (w_g + (o - 64) * CC);
            wl[o * 17 + k] = wp[k0 + k];
        }
        {
            int k = tid >> 4, hw4 = tid & 15;   // 16 k rows x 16 float4
            int c = k0 + k;
            float4 v = *(const float4*)&x[((size_t)(b * CC + c)) * HWN + hw0 + hw4 * 4];
            float a = ab_s[c], bc = ab_s[CC + c];
            float4 r;
            r.x = fmaxf(fmaf(a, v.x, bc), 0.f);
            r.y = fmaxf(fmaf(a, v.y, bc), 0.f);
            r.z = fmaxf(fmaf(a, v.z, bc), 0.f);
            r.w = fmaxf(fmaf(a, v.w, bc), 0.f);
            *(float4*)&xl[k * 64 + hw4 * 4] = r;
        }
        __syncthreads();
        #pragma unroll
        for (int k = 0; k < 16; ++k) {
            float4 xv = *(const float4*)&xl[k * 64 + tx * 4];
            #pragma unroll
            for (int j = 0; j < 8; ++j) {
                float wv = wl[(ty * 8 + j) * 17 + k];
                acc[j][0] = fmaf(wv, xv.x, acc[j][0]);
                acc[j][1] = fmaf(wv, xv.y, acc[j][1]);
                acc[j][2] = fmaf(wv, xv.z, acc[j][2]);
                acc[j][3] = fmaf(wv, xv.w, acc[j][3]);
            }
        }
        __syncthreads();
    }
    #pragma unroll
    for (int j = 0; j < 8; ++j) {
        int o = ty * 8 + j;
        float bias = (o < 32) ? b_t[o] : (o < 64) ? b_p[o - 32] : b_g[o - 64];
        float4 r = make_float4(acc[j][0] + bias, acc[j][1] + bias,
                               acc[j][2] + bias, acc[j][3] + bias);
        *(float4*)&conv1[((size_t)(b * 128 + o)) * HWN + hw0 + tx * 4] = r;
    }
}

// ---------------- kernel 3: fused maxpool + partial S = phi_p . g_p^T ----------------
// grid (14, B): m-chunks of 56 pooled positions; block 256
// conv1 channels: [0,32)=theta, [32,64)=phi, [64,128)=g
__global__ __launch_bounds__(256) void k_spart(const float* __restrict__ conv1,
                                               float* __restrict__ spart) {
    int cx = blockIdx.x;   // 0..13
    int b  = blockIdx.y;
    int tid = threadIdx.x;
    __shared__ float pl[96 * 60];   // rows: 0..31 phi_p, 32..95 g_p; stride 60

    #pragma unroll
    for (int i = 0; i < 21; ++i) {
        int e = tid + i * 256;            // 5376 = 96*56
        int ch = e / 56, mm = e - ch * 56;
        int m = cx * 56 + mm;
        int mh = m / 28, mw = m - mh * 28;
        const float* p = conv1 + ((size_t)(b * 128 + 32 + ch)) * HWN + mh * 112 + mw * 2;
        pl[ch * 60 + mm] = fmaxf(fmaxf(p[0], p[1]), fmaxf(p[56], p[57]));
    }
    __syncthreads();

    int cg = tid & 63;
    int cib = tid >> 6;    // 0..3
    float acc[8];
    #pragma unroll
    for (int i = 0; i < 8; ++i) acc[i] = 0.f;
    const float* pb = &pl[(32 + cg) * 60];
    for (int mm4 = 0; mm4 < 14; ++mm4) {
        float4 bv = *(const float4*)&pb[mm4 * 4];
        #pragma unroll
        for (int i = 0; i < 8; ++i) {
            float4 av = *(const float4*)&pl[(cib + 4 * i) * 60 + mm4 * 4];
            acc[i] = fmaf(av.x, bv.x, acc[i]);
            acc[i] = fmaf(av.y, bv.y, acc[i]);
            acc[i] = fmaf(av.z, bv.z, acc[i]);
            acc[i] = fmaf(av.w, bv.w, acc[i]);
        }
    }
    float* out = spart + ((size_t)(b * 14 + cx)) * 2048;
    #pragma unroll
    for (int i = 0; i < 8; ++i) out[tid + i * 256] = acc[i];
}

// ---------------- kernel 4: y = theta^T S / Np + BN2 partial stats ----------------
// grid (7, B); block 448; each thread: 4 hw x 16 cg
__global__ __launch_bounds__(448) void k_y(const float* __restrict__ conv1,
                                           const float* __restrict__ spart,
                                           float* __restrict__ y,
                                           float* __restrict__ bn2acc) {
    int bx = blockIdx.x;
    int b  = blockIdx.y;
    int tid = threadIdx.x;
    __shared__ float S[2048];       // [ci][cg]
    __shared__ float shs[64], shq[64];

    for (int id = tid; id < 2048; id += 448) {
        const float* p = spart + (size_t)b * 14 * 2048 + id;
        float s = 0.f;
        #pragma unroll
        for (int j = 0; j < 14; ++j) s += p[j * 2048];
        S[id] = s * (1.0f / NPP);
    }
    if (tid < 64) { shs[tid] = 0.f; shq[tid] = 0.f; }
    __syncthreads();

    int lm  = tid % 112;
    int cgb = (tid / 112) * 16;
    int hw4 = bx * 448 + lm * 4;

    float4 acc[16];
    #pragma unroll
    for (int j = 0; j < 16; ++j) acc[j] = make_float4(0.f, 0.f, 0.f, 0.f);

    const float* th = conv1 + (size_t)b * 128 * HWN + hw4;
    for (int ci = 0; ci < NCI; ++ci) {
        float4 t = *(const float4*)(th + (size_t)ci * HWN);
        const float* sp = &S[ci * 64 + cgb];
        #pragma unroll
        for (int j = 0; j < 16; ++j) {
            float sv = sp[j];
            acc[j].x = fmaf(t.x, sv, acc[j].x);
            acc[j].y = fmaf(t.y, sv, acc[j].y);
            acc[j].z = fmaf(t.z, sv, acc[j].z);
            acc[j].w = fmaf(t.w, sv, acc[j].w);
        }
    }
    #pragma unroll
    for (int j = 0; j < 16; ++j) {
        int cg = cgb + j;
        *(float4*)&y[((size_t)(b * NCG + cg)) * HWN + hw4] = acc[j];
        float s = acc[j].x + acc[j].y + acc[j].z + acc[j].w;
        float q = acc[j].x * acc[j].x + acc[j].y * acc[j].y +
                  acc[j].z * acc[j].z + acc[j].w * acc[j].w;
        atomicAdd(&shs[cg], s);
        atomicAdd(&shq[cg], q);
    }
    __syncthreads();
    if (tid < 64) {
        atomicAdd(&bn2acc[tid], shs[tid]);
        atomicAdd(&bn2acc[64 + tid], shq[tid]);
    }
}

// ---------------- kernel 5: BN2+ReLU+conv1x1(z) + residual ----------------
// grid (49, B, 2); block 256; tile 128 co x 64 hw; K=64 (full)
__global__ __launch_bounds__(256) void k_convz(const float* __restrict__ y,
                                               const float* __restrict__ bn2acc,
                                               const float* __restrict__ gamma,
                                               const float* __restrict__ beta,
                                               const float* __restrict__ w_z,
                                               const float* __restrict__ b_z,
                                               const float* __restrict__ x,
                                               float* __restrict__ out) {
    int b = blockIdx.y;
    int hw0 = blockIdx.x * 64;
    int coh = blockIdx.z * 128;
    int tid = threadIdx.x;
    int tx = tid & 15;
    int ty = tid >> 4;

    __shared__ float ab2_s[128];
    __shared__ float wl[128 * 65];   // [co][k], stride 65
    __shared__ float yl[64 * 64];    // [k][hw]

    if (tid < 64) {   // fold BN2 finalize in
        const float inv = 1.0f / (BB * HWN);
        float mean = bn2acc[tid] * inv;
        float var  = bn2acc[64 + tid] * inv - mean * mean;
        float a = gamma[tid] * rsqrtf(var + 1e-5f);
        ab2_s[tid] = a;
        ab2_s[64 + tid] = beta[tid] - mean * a;
    }

    #pragma unroll
    for (int i = 0; i < 32; ++i) {
        int e = tid + i * 256;   // 8192
        int co = e >> 6, k = e & 63;
        wl[co * 65 + k] = w_z[(coh + co) * 64 + k];
    }
    __syncthreads();
    #pragma unroll
    for (int i = 0; i < 16; ++i) {
        int e = tid + i * 256;   // 4096
        int k = e >> 6, hw = e & 63;
        float v = y[((size_t)(b * NCG + k)) * HWN + hw0 + hw];
        yl[k * 64 + hw] = fmaxf(fmaf(ab2_s[k], v, ab2_s[64 + k]), 0.f);
    }
    __syncthreads();

    float acc[8][4];
    #pragma unroll
    for (int j = 0; j < 8; ++j)
        for (int u = 0; u < 4; ++u) acc[j][u] = 0.f;

    #pragma unroll
    for (int k = 0; k < 64; ++k) {
        float4 yv = *(const float4*)&yl[k * 64 + tx * 4];
        #pragma unroll
        for (int j = 0; j < 8; ++j) {
            float wv = wl[(ty * 8 + j) * 65 + k];
            acc[j][0] = fmaf(wv, yv.x, acc[j][0]);
            acc[j][1] = fmaf(wv, yv.y, acc[j][1]);
            acc[j][2] = fmaf(wv, yv.z, acc[j][2]);
            acc[j][3] = fmaf(wv, yv.w, acc[j][3]);
        }
    }
    #pragma unroll
    for (int j = 0; j < 8; ++j) {
        int co = coh + ty * 8 + j;
        size_t base = ((size_t)(b * CC + co)) * HWN + hw0 + tx * 4;
        float4 xv = *(const float4*)&x[base];
        float bz = b_z[co];
        float4 r = make_float4(acc[j][0] + bz + xv.x, acc[j][1] + bz + xv.y,
                               acc[j][2] + bz + xv.z, acc[j][3] + bz + xv.w);
        *(float4*)&out[base] = r;
    }
}

extern "C" void kernel_launch(void* const* d_in, const int* in_sizes, int n_in,
                              void* d_out, int out_size, void* d_ws, size_t ws_size,
                              hipStream_t stream) {
    (void)in_sizes; (void)n_in; (void)out_size; (void)ws_size;
    const float* x   = (const float*)d_in[0];
    const float* g1  = (const float*)d_in[1];
    const float* b1  = (const float*)d_in[2];
    const float* w_g = (const float*)d_in[3];
    const float* b_g = (const float*)d_in[4];
    const float* w_t = (const float*)d_in[5];
    const float* b_t = (const float*)d_in[6];
    const float* w_p = (const float*)d_in[7];
    const float* b_p = (const float*)d_in[8];
    const float* g2  = (const float*)d_in[9];
    const float* b2  = (const float*)d_in[10];
    const float* w_z = (const float*)d_in[11];
    const float* b_z = (const float*)d_in[12];
    float* out = (float*)d_out;

    float* ws     = (float*)d_ws;
    float* bn1acc = ws;                                  // 512
    float* bn2acc = ws + 512;                            // 128
    float* conv1  = ws + 1024;                           // 16*128*3136
    float* spart  = conv1 + (size_t)BB * 128 * HWN;      // 16*14*2048
    float* yb     = spart + (size_t)BB * 14 * 2048;      // 16*64*3136

    k_zero  <<<dim3(1),          dim3(256), 0, stream>>>(bn1acc);
    k_bn1a  <<<dim3(BB * CC),    dim3(256), 0, stream>>>(x, bn1acc);
    k_conv1 <<<dim3(49, BB),     dim3(256), 0, stream>>>(x, bn1acc, g1, b1, w_g, b_g, w_t, b_t, w_p, b_p, conv1);
    k_spart <<<dim3(14, BB),     dim3(256), 0, stream>>>(conv1, spart);
    k_y     <<<dim3(7, BB),      dim3(448), 0, stream>>>(conv1, spart, yb, bn2acc);
    k_convz <<<dim3(49, BB, 2),  dim3(256), 0, stream>>>(yb, bn2acc, g2, b2, w_z, b_z, x, out);
}

// Round 3
// 215.983 us; speedup vs baseline: 1.4622x; 1.2201x over previous
//
#include <hip/hip_runtime.h>
#include <hip/hip_bf16.h>

#define BB 16
#define CC 256
#define HWN 3136
#define NCG 64
#define NCI 32
#define NPP 784   // 28*28

typedef __attribute__((ext_vector_type(8))) short short8;
typedef __attribute__((ext_vector_type(4))) float floatx4;

__device__ __forceinline__ unsigned short f2bf(float f) {
    union { __hip_bfloat16 h; unsigned short u; } cv;
    cv.h = __float2bfloat16(f);
    return cv.u;
}
__device__ __forceinline__ float bf2f(unsigned short u) {
    return __uint_as_float(((unsigned)u) << 16);
}

// ---------------- kernel P: weight cat->bf16 + zero accumulators ----------------
__global__ __launch_bounds__(256) void k_prep(const float* __restrict__ w_t,
                                              const float* __restrict__ w_p,
                                              const float* __restrict__ w_g,
                                              unsigned short* __restrict__ wcat,
                                              float* __restrict__ accs) {
    int o = blockIdx.x;    // 0..127
    int c = threadIdx.x;   // 0..255
    const float* src = (o < 32) ? (w_t + o * CC)
                      : (o < 64) ? (w_p + (o - 32) * CC)
                                 : (w_g + (o - 64) * CC);
    wcat[o * CC + c] = f2bf(src[c]);
    if (o == 0) {
        for (int i = c; i < 640; i += 256) accs[i] = 0.f;
    }
}

// ---------------- kernel 1: BN1 partial sums (one block per (b,c)) ----------------
__global__ __launch_bounds__(256) void k_bn1a(const float* __restrict__ x,
                                              float* __restrict__ acc) {
    int blk = blockIdx.x;           // b*CC + c
    int c = blk & (CC - 1);
    const float4* p = (const float4*)(x + (size_t)blk * HWN);
    int tid = threadIdx.x;
    float s = 0.f, q = 0.f;
    #pragma unroll
    for (int i = tid; i < 784; i += 256) {
        float4 v = p[i];
        s += v.x + v.y + v.z + v.w;
        q += v.x * v.x + v.y * v.y + v.z * v.z + v.w * v.w;
    }
    #pragma unroll
    for (int off = 32; off > 0; off >>= 1) {
        s += __shfl_down(s, off);
        q += __shfl_down(q, off);
    }
    __shared__ float sh[8];
    int wid = tid >> 6, lane = tid & 63;
    if (lane == 0) { sh[wid] = s; sh[4 + wid] = q; }
    __syncthreads();
    if (tid == 0) {
        atomicAdd(&acc[c], sh[0] + sh[1] + sh[2] + sh[3]);
        atomicAdd(&acc[CC + c], sh[4] + sh[5] + sh[6] + sh[7]);
    }
}

// ---------------- kernel 2: fused BN1+ReLU+conv1x1 via bf16 MFMA ----------------
// grid (49, B); block 256 (4 waves); tile M=128 o x N=64 hw; K=256 in 8 steps
// LDS A: [o][32k] bf16, 64B rows (global_load_lds, lane-contiguous)
// LDS B: [hw][32k] bf16, 64B rows (transposed staging)
__global__ __launch_bounds__(256) void k_conv1(const float* __restrict__ x,
                                               const unsigned short* __restrict__ wcat,
                                               const float* __restrict__ bn1acc,
                                               const float* __restrict__ gamma,
                                               const float* __restrict__ beta,
                                               const float* __restrict__ b_g,
                                               const float* __restrict__ b_t,
                                               const float* __restrict__ b_p,
                                               unsigned short* __restrict__ conv1) {
    int b = blockIdx.y;
    int hw0 = blockIdx.x * 64;
    int tid = threadIdx.x;
    int wv = tid >> 6, ln = tid & 63;

    __shared__ unsigned short Asmem[128 * 32];
    __shared__ unsigned short Bsmem[64 * 32];
    __shared__ float ab_s[512];
    __shared__ float bias_s[128];

    {   // fold BN1 finalize
        const float inv = 1.0f / (BB * HWN);
        float mean = bn1acc[tid] * inv;
        float var  = bn1acc[CC + tid] * inv - mean * mean;
        float a = gamma[tid] * rsqrtf(var + 1e-5f);
        ab_s[tid] = a;
        ab_s[CC + tid] = beta[tid] - mean * a;
    }
    if (tid < 128) {
        int o = tid;
        bias_s[o] = (o < 32) ? b_t[o] : (o < 64) ? b_p[o - 32] : b_g[o - 64];
    }
    __syncthreads();

    floatx4 acc[2][4];
    #pragma unroll
    for (int mt = 0; mt < 2; ++mt)
        for (int nt = 0; nt < 4; ++nt)
            acc[mt][nt] = (floatx4){0.f, 0.f, 0.f, 0.f};

    int p   = tid & 15;    // c-pair index (c = k0 + 2p, 2p+1)
    int hwq = tid >> 4;    // hw-quad 0..15
    const float* xb = x + (size_t)(b * CC) * HWN + hw0 + hwq * 4;

    int col = ln & 15, quad = ln >> 4;

    for (int k0 = 0; k0 < CC; k0 += 32) {
        // ---- stage A (weights) via async global->LDS, 2 instr/wave ----
        #pragma unroll
        for (int i = 0; i < 2; ++i) {
            int row = wv * 32 + i * 16 + (ln >> 2);
            int q   = ln & 3;
            const unsigned short* gp = wcat + row * CC + k0 + q * 8;   // 16B per lane
            __builtin_amdgcn_global_load_lds(
                (const __attribute__((address_space(1))) unsigned int*)gp,
                (__attribute__((address_space(3))) unsigned int*)&Asmem[(wv * 2 + i) * 512],
                16, 0, 0);
        }
        // ---- stage B: x float4 loads -> BN+ReLU -> bf16 pack -> [hw][k] LDS ----
        {
            int c0 = k0 + 2 * p;
            float4 v0 = *(const float4*)(xb + (size_t)c0 * HWN);
            float4 v1 = *(const float4*)(xb + (size_t)(c0 + 1) * HWN);
            float a0 = ab_s[c0],     d0 = ab_s[CC + c0];
            float a1 = ab_s[c0 + 1], d1 = ab_s[CC + c0 + 1];
            float r0[4] = { fmaxf(fmaf(a0, v0.x, d0), 0.f), fmaxf(fmaf(a0, v0.y, d0), 0.f),
                            fmaxf(fmaf(a0, v0.z, d0), 0.f), fmaxf(fmaf(a0, v0.w, d0), 0.f) };
            float r1[4] = { fmaxf(fmaf(a1, v1.x, d1), 0.f), fmaxf(fmaf(a1, v1.y, d1), 0.f),
                            fmaxf(fmaf(a1, v1.z, d1), 0.f), fmaxf(fmaf(a1, v1.w, d1), 0.f) };
            unsigned int* bw = (unsigned int*)Bsmem;
            #pragma unroll
            for (int i = 0; i < 4; ++i) {
                unsigned int w = (unsigned int)f2bf(r0[i]) | ((unsigned int)f2bf(r1[i]) << 16);
                bw[(hwq * 4 + i) * 16 + p] = w;   // row hw, word = c-pair p
            }
        }
        __syncthreads();   // drains vmcnt (global_load_lds) + lgkm

        // ---- MFMA: 2 m-tiles x 4 n-tiles ----
        short8 af0 = *(const short8*)&Asmem[(wv * 32 +      (ln & 15)) * 32 + quad * 8];
        short8 af1 = *(const short8*)&Asmem[(wv * 32 + 16 + (ln & 15)) * 32 + quad * 8];
        #pragma unroll
        for (int nt = 0; nt < 4; ++nt) {
            short8 bf = *(const short8*)&Bsmem[(nt * 16 + (ln & 15)) * 32 + quad * 8];
            acc[0][nt] = __builtin_amdgcn_mfma_f32_16x16x32_bf16(af0, bf, acc[0][nt], 0, 0, 0);
            acc[1][nt] = __builtin_amdgcn_mfma_f32_16x16x32_bf16(af1, bf, acc[1][nt], 0, 0, 0);
        }
        __syncthreads();
    }

    // ---- epilogue: bias + store bf16 ----
    #pragma unroll
    for (int mt = 0; mt < 2; ++mt) {
        int obase = wv * 32 + mt * 16 + quad * 4;
        #pragma unroll
        for (int r = 0; r < 4; ++r) {
            int o = obase + r;
            float bias = bias_s[o];
            #pragma unroll
            for (int nt = 0; nt < 4; ++nt) {
                float val = acc[mt][nt][r] + bias;
                conv1[((size_t)(b * 128 + o)) * HWN + hw0 + nt * 16 + col] = f2bf(val);
            }
        }
    }
}

// ---------------- kernel 3: fused maxpool + partial S = phi_p . g_p^T ----------------
__global__ __launch_bounds__(256) void k_spart(const unsigned short* __restrict__ conv1,
                                               float* __restrict__ spart) {
    int cx = blockIdx.x;   // 0..13
    int b  = blockIdx.y;
    int tid = threadIdx.x;
    __shared__ float pl[96 * 60];   // rows: 0..31 phi_p, 32..95 g_p; stride 60

    #pragma unroll
    for (int i = 0; i < 21; ++i) {
        int e = tid + i * 256;            // 5376 = 96*56
        int ch = e / 56, mm = e - ch * 56;
        int m = cx * 56 + mm;
        int mh = m / 28, mw = m - mh * 28;
        const unsigned short* p = conv1 + ((size_t)(b * 128 + 32 + ch)) * HWN + mh * 112 + mw * 2;
        pl[ch * 60 + mm] = fmaxf(fmaxf(bf2f(p[0]), bf2f(p[1])),
                                 fmaxf(bf2f(p[56]), bf2f(p[57])));
    }
    __syncthreads();

    int cg = tid & 63;
    int cib = tid >> 6;    // 0..3
    float acc[8];
    #pragma unroll
    for (int i = 0; i < 8; ++i) acc[i] = 0.f;
    const float* pb = &pl[(32 + cg) * 60];
    for (int mm4 = 0; mm4 < 14; ++mm4) {
        float4 bv = *(const float4*)&pb[mm4 * 4];
        #pragma unroll
        for (int i = 0; i < 8; ++i) {
            float4 av = *(const float4*)&pl[(cib + 4 * i) * 60 + mm4 * 4];
            acc[i] = fmaf(av.x, bv.x, acc[i]);
            acc[i] = fmaf(av.y, bv.y, acc[i]);
            acc[i] = fmaf(av.z, bv.z, acc[i]);
            acc[i] = fmaf(av.w, bv.w, acc[i]);
        }
    }
    float* out = spart + ((size_t)(b * 14 + cx)) * 2048;
    #pragma unroll
    for (int i = 0; i < 8; ++i) out[tid + i * 256] = acc[i];
}

// ---------------- kernel 4: y = theta^T S / Np + BN2 partial stats ----------------
__global__ __launch_bounds__(448) void k_y(const unsigned short* __restrict__ conv1,
                                           const float* __restrict__ spart,
                                           float* __restrict__ y,
                                           float* __restrict__ bn2acc) {
    int bx = blockIdx.x;
    int b  = blockIdx.y;
    int tid = threadIdx.x;
    __shared__ float S[2048];       // [ci][cg]
    __shared__ float shs[64], shq[64];

    for (int id = tid; id < 2048; id += 448) {
        const float* p = spart + (size_t)b * 14 * 2048 + id;
        float s = 0.f;
        #pragma unroll
        for (int j = 0; j < 14; ++j) s += p[j * 2048];
        S[id] = s * (1.0f / NPP);
    }
    if (tid < 64) { shs[tid] = 0.f; shq[tid] = 0.f; }
    __syncthreads();

    int lm  = tid % 112;
    int cgb = (tid / 112) * 16;
    int hw4 = bx * 448 + lm * 4;

    float4 acc[16];
    #pragma unroll
    for (int j = 0; j < 16; ++j) acc[j] = make_float4(0.f, 0.f, 0.f, 0.f);

    const unsigned short* th = conv1 + (size_t)b * 128 * HWN + hw4;
    for (int ci = 0; ci < NCI; ++ci) {
        ushort4 tv = *(const ushort4*)(th + (size_t)ci * HWN);
        float4 t = make_float4(bf2f(tv.x), bf2f(tv.y), bf2f(tv.z), bf2f(tv.w));
        const float* sp = &S[ci * 64 + cgb];
        #pragma unroll
        for (int j = 0; j < 16; ++j) {
            float sv = sp[j];
            acc[j].x = fmaf(t.x, sv, acc[j].x);
            acc[j].y = fmaf(t.y, sv, acc[j].y);
            acc[j].z = fmaf(t.z, sv, acc[j].z);
            acc[j].w = fmaf(t.w, sv, acc[j].w);
        }
    }
    #pragma unroll
    for (int j = 0; j < 16; ++j) {
        int cg = cgb + j;
        *(float4*)&y[((size_t)(b * NCG + cg)) * HWN + hw4] = acc[j];
        float s = acc[j].x + acc[j].y + acc[j].z + acc[j].w;
        float q = acc[j].x * acc[j].x + acc[j].y * acc[j].y +
                  acc[j].z * acc[j].z + acc[j].w * acc[j].w;
        atomicAdd(&shs[cg], s);
        atomicAdd(&shq[cg], q);
    }
    __syncthreads();
    if (tid < 64) {
        atomicAdd(&bn2acc[tid], shs[tid]);
        atomicAdd(&bn2acc[64 + tid], shq[tid]);
    }
}

// ---------------- kernel 5: BN2+ReLU+conv1x1(z) + residual ----------------
__global__ __launch_bounds__(256) void k_convz(const float* __restrict__ y,
                                               const float* __restrict__ bn2acc,
                                               const float* __restrict__ gamma,
                                               const float* __restrict__ beta,
                                               const float* __restrict__ w_z,
                                               const float* __restrict__ b_z,
                                               const float* __restrict__ x,
                                               float* __restrict__ out) {
    int b = blockIdx.y;
    int hw0 = blockIdx.x * 64;
    int coh = blockIdx.z * 128;
    int tid = threadIdx.x;
    int tx = tid & 15;
    int ty = tid >> 4;

    __shared__ float ab2_s[128];
    __shared__ float wl[128 * 65];   // [co][k], stride 65
    __shared__ float yl[64 * 64];    // [k][hw]

    if (tid < 64) {   // fold BN2 finalize in
        const float inv = 1.0f / (BB * HWN);
        float mean = bn2acc[tid] * inv;
        float var  = bn2acc[64 + tid] * inv - mean * mean;
        float a = gamma[tid] * rsqrtf(var + 1e-5f);
        ab2_s[tid] = a;
        ab2_s[64 + tid] = beta[tid] - mean * a;
    }

    #pragma unroll
    for (int i = 0; i < 32; ++i) {
        int e = tid + i * 256;   // 8192
        int co = e >> 6, k = e & 63;
        wl[co * 65 + k] = w_z[(coh + co) * 64 + k];
    }
    __syncthreads();
    #pragma unroll
    for (int i = 0; i < 16; ++i) {
        int e = tid + i * 256;   // 4096
        int k = e >> 6, hw = e & 63;
        float v = y[((size_t)(b * NCG + k)) * HWN + hw0 + hw];
        yl[k * 64 + hw] = fmaxf(fmaf(ab2_s[k], v, ab2_s[64 + k]), 0.f);
    }
    __syncthreads();

    float acc[8][4];
    #pragma unroll
    for (int j = 0; j < 8; ++j)
        for (int u = 0; u < 4; ++u) acc[j][u] = 0.f;

    #pragma unroll
    for (int k = 0; k < 64; ++k) {
        float4 yv = *(const float4*)&yl[k * 64 + tx * 4];
        #pragma unroll
        for (int j = 0; j < 8; ++j) {
            float wv = wl[(ty * 8 + j) * 65 + k];
            acc[j][0] = fmaf(wv, yv.x, acc[j][0]);
            acc[j][1] = fmaf(wv, yv.y, acc[j][1]);
            acc[j][2] = fmaf(wv, yv.z, acc[j][2]);
            acc[j][3] = fmaf(wv, yv.w, acc[j][3]);
        }
    }
    #pragma unroll
    for (int j = 0; j < 8; ++j) {
        int co = coh + ty * 8 + j;
        size_t base = ((size_t)(b * CC + co)) * HWN + hw0 + tx * 4;
        float4 xv = *(const float4*)&x[base];
        float bz = b_z[co];
        float4 r = make_float4(acc[j][0] + bz + xv.x, acc[j][1] + bz + xv.y,
                               acc[j][2] + bz + xv.z, acc[j][3] + bz + xv.w);
        *(float4*)&out[base] = r;
    }
}

extern "C" void kernel_launch(void* const* d_in, const int* in_sizes, int n_in,
                              void* d_out, int out_size, void* d_ws, size_t ws_size,
                              hipStream_t stream) {
    (void)in_sizes; (void)n_in; (void)out_size; (void)ws_size;
    const float* x   = (const float*)d_in[0];
    const float* g1  = (const float*)d_in[1];
    const float* b1  = (const float*)d_in[2];
    const float* w_g = (const float*)d_in[3];
    const float* b_g = (const float*)d_in[4];
    const float* w_t = (const float*)d_in[5];
    const float* b_t = (const float*)d_in[6];
    const float* w_p = (const float*)d_in[7];
    const float* b_p = (const float*)d_in[8];
    const float* g2  = (const float*)d_in[9];
    const float* b2  = (const float*)d_in[10];
    const float* w_z = (const float*)d_in[11];
    const float* b_z = (const float*)d_in[12];
    float* out = (float*)d_out;

    float* ws     = (float*)d_ws;
    float* bn1acc = ws;                                   // 512
    float* bn2acc = ws + 512;                             // 128
    unsigned short* wcat  = (unsigned short*)(ws + 1024); // 128*256 bf16 = 16384 floats
    unsigned short* conv1 = (unsigned short*)(ws + 17408);// 16*128*3136 bf16 = 3211264 floats
    float* spart  = ws + 3228672;                         // 16*14*2048
    float* yb     = ws + 3687424;                         // 16*64*3136

    k_prep  <<<dim3(128),        dim3(256), 0, stream>>>(w_t, w_p, w_g, wcat, ws);
    k_bn1a  <<<dim3(BB * CC),    dim3(256), 0, stream>>>(x, bn1acc);
    k_conv1 <<<dim3(49, BB),     dim3(256), 0, stream>>>(x, wcat, bn1acc, g1, b1, b_g, b_t, b_p, conv1);
    k_spart <<<dim3(14, BB),     dim3(256), 0, stream>>>(conv1, spart);
    k_y     <<<dim3(7, BB),      dim3(448), 0, stream>>>(conv1, spart, yb, bn2acc);
    k_convz <<<dim3(49, BB, 2),  dim3(256), 0, stream>>>(yb, bn2acc, g2, b2, w_z, b_z, x, out);
}

// Round 4
// 198.850 us; speedup vs baseline: 1.5882x; 1.0862x over previous
//
#include <hip/hip_runtime.h>
#include <hip/hip_bf16.h>

#define BB 16
#define CC 256
#define HWN 3136
#define NCG 64
#define NCI 32
#define NPP 784   // 28*28

typedef __attribute__((ext_vector_type(8))) short short8;
typedef __attribute__((ext_vector_type(4))) float floatx4;

__device__ __forceinline__ unsigned short f2bf(float f) {
    union { __hip_bfloat16 h; unsigned short u; } cv;
    cv.h = __float2bfloat16(f);
    return cv.u;
}
__device__ __forceinline__ float bf2f(unsigned short u) {
    return __uint_as_float(((unsigned)u) << 16);
}

// ---------------- kernel P: weights->bf16 (+swizzled w_z image) + zero accs ----------------
// wcat: [128][256] bf16 flat. wzb: [256][72] bf16 padded-row image for k_convz LDS DMA.
__global__ __launch_bounds__(256) void k_prep(const float* __restrict__ w_t,
                                              const float* __restrict__ w_p,
                                              const float* __restrict__ w_g,
                                              const float* __restrict__ w_z,
                                              unsigned short* __restrict__ wcat,
                                              unsigned short* __restrict__ wzb,
                                              float* __restrict__ accs) {
    int o = blockIdx.x;    // 0..127
    int c = threadIdx.x;   // 0..255
    const float* src = (o < 32) ? (w_t + o * CC)
                      : (o < 64) ? (w_p + (o - 32) * CC)
                                 : (w_g + (o - 64) * CC);
    wcat[o * CC + c] = f2bf(src[c]);
    {   // w_z: rows 2o, 2o+1 of padded [256][72] image
        int r = o * 2 + (c >> 7);
        int kk = c & 127;
        if (kk < 72)
            wzb[r * 72 + kk] = (kk < 64) ? f2bf(w_z[r * 64 + kk]) : (unsigned short)0;
    }
    if (o == 0) {
        for (int i = c; i < 640; i += 256) accs[i] = 0.f;
    }
}

// ---------------- kernel 1: BN1 partial sums (one block per (b,c)) ----------------
__global__ __launch_bounds__(256) void k_bn1a(const float* __restrict__ x,
                                              float* __restrict__ acc) {
    int blk = blockIdx.x;           // b*CC + c
    int c = blk & (CC - 1);
    const float4* p = (const float4*)(x + (size_t)blk * HWN);
    int tid = threadIdx.x;
    float s = 0.f, q = 0.f;
    #pragma unroll
    for (int i = tid; i < 784; i += 256) {
        float4 v = p[i];
        s += v.x + v.y + v.z + v.w;
        q += v.x * v.x + v.y * v.y + v.z * v.z + v.w * v.w;
    }
    #pragma unroll
    for (int off = 32; off > 0; off >>= 1) {
        s += __shfl_down(s, off);
        q += __shfl_down(q, off);
    }
    __shared__ float sh[8];
    int wid = tid >> 6, lane = tid & 63;
    if (lane == 0) { sh[wid] = s; sh[4 + wid] = q; }
    __syncthreads();
    if (tid == 0) {
        atomicAdd(&acc[c], sh[0] + sh[1] + sh[2] + sh[3]);
        atomicAdd(&acc[CC + c], sh[4] + sh[5] + sh[6] + sh[7]);
    }
}

// ---------------- kernel 2: fused BN1+ReLU+conv1x1 via bf16 MFMA ----------------
__global__ __launch_bounds__(256) void k_conv1(const float* __restrict__ x,
                                               const unsigned short* __restrict__ wcat,
                                               const float* __restrict__ bn1acc,
                                               const float* __restrict__ gamma,
                                               const float* __restrict__ beta,
                                               const float* __restrict__ b_g,
                                               const float* __restrict__ b_t,
                                               const float* __restrict__ b_p,
                                               unsigned short* __restrict__ conv1) {
    int b = blockIdx.y;
    int hw0 = blockIdx.x * 64;
    int tid = threadIdx.x;
    int wv = tid >> 6, ln = tid & 63;

    __shared__ unsigned short Asmem[128 * 32];
    __shared__ unsigned short Bsmem[64 * 32];
    __shared__ float ab_s[512];
    __shared__ float bias_s[128];

    {   // fold BN1 finalize
        const float inv = 1.0f / (BB * HWN);
        float mean = bn1acc[tid] * inv;
        float var  = bn1acc[CC + tid] * inv - mean * mean;
        float a = gamma[tid] * rsqrtf(var + 1e-5f);
        ab_s[tid] = a;
        ab_s[CC + tid] = beta[tid] - mean * a;
    }
    if (tid < 128) {
        int o = tid;
        bias_s[o] = (o < 32) ? b_t[o] : (o < 64) ? b_p[o - 32] : b_g[o - 64];
    }
    __syncthreads();

    floatx4 acc[2][4];
    #pragma unroll
    for (int mt = 0; mt < 2; ++mt)
        for (int nt = 0; nt < 4; ++nt)
            acc[mt][nt] = (floatx4){0.f, 0.f, 0.f, 0.f};

    int p   = tid & 15;    // c-pair index
    int hwq = tid >> 4;    // hw-quad 0..15
    const float* xb = x + (size_t)(b * CC) * HWN + hw0 + hwq * 4;

    int col = ln & 15, quad = ln >> 4;

    for (int k0 = 0; k0 < CC; k0 += 32) {
        #pragma unroll
        for (int i = 0; i < 2; ++i) {
            int row = wv * 32 + i * 16 + (ln >> 2);
            int q   = ln & 3;
            const unsigned short* gp = wcat + row * CC + k0 + q * 8;
            __builtin_amdgcn_global_load_lds(
                (const __attribute__((address_space(1))) unsigned int*)gp,
                (__attribute__((address_space(3))) unsigned int*)&Asmem[(wv * 2 + i) * 512],
                16, 0, 0);
        }
        {
            int c0 = k0 + 2 * p;
            float4 v0 = *(const float4*)(xb + (size_t)c0 * HWN);
            float4 v1 = *(const float4*)(xb + (size_t)(c0 + 1) * HWN);
            float a0 = ab_s[c0],     d0 = ab_s[CC + c0];
            float a1 = ab_s[c0 + 1], d1 = ab_s[CC + c0 + 1];
            float r0[4] = { fmaxf(fmaf(a0, v0.x, d0), 0.f), fmaxf(fmaf(a0, v0.y, d0), 0.f),
                            fmaxf(fmaf(a0, v0.z, d0), 0.f), fmaxf(fmaf(a0, v0.w, d0), 0.f) };
            float r1[4] = { fmaxf(fmaf(a1, v1.x, d1), 0.f), fmaxf(fmaf(a1, v1.y, d1), 0.f),
                            fmaxf(fmaf(a1, v1.z, d1), 0.f), fmaxf(fmaf(a1, v1.w, d1), 0.f) };
            unsigned int* bw = (unsigned int*)Bsmem;
            #pragma unroll
            for (int i = 0; i < 4; ++i) {
                unsigned int w = (unsigned int)f2bf(r0[i]) | ((unsigned int)f2bf(r1[i]) << 16);
                bw[(hwq * 4 + i) * 16 + p] = w;
            }
        }
        __syncthreads();

        short8 af0 = *(const short8*)&Asmem[(wv * 32 +      (ln & 15)) * 32 + quad * 8];
        short8 af1 = *(const short8*)&Asmem[(wv * 32 + 16 + (ln & 15)) * 32 + quad * 8];
        #pragma unroll
        for (int nt = 0; nt < 4; ++nt) {
            short8 bf = *(const short8*)&Bsmem[(nt * 16 + (ln & 15)) * 32 + quad * 8];
            acc[0][nt] = __builtin_amdgcn_mfma_f32_16x16x32_bf16(af0, bf, acc[0][nt], 0, 0, 0);
            acc[1][nt] = __builtin_amdgcn_mfma_f32_16x16x32_bf16(af1, bf, acc[1][nt], 0, 0, 0);
        }
        __syncthreads();
    }

    #pragma unroll
    for (int mt = 0; mt < 2; ++mt) {
        int obase = wv * 32 + mt * 16 + quad * 4;
        #pragma unroll
        for (int r = 0; r < 4; ++r) {
            int o = obase + r;
            float bias = bias_s[o];
            #pragma unroll
            for (int nt = 0; nt < 4; ++nt) {
                float val = acc[mt][nt][r] + bias;
                conv1[((size_t)(b * 128 + o)) * HWN + hw0 + nt * 16 + col] = f2bf(val);
            }
        }
    }
}

// ---------------- kernel 3: fused maxpool + partial S = phi_p . g_p^T ----------------
__global__ __launch_bounds__(256) void k_spart(const unsigned short* __restrict__ conv1,
                                               float* __restrict__ spart) {
    int cx = blockIdx.x;   // 0..13
    int b  = blockIdx.y;
    int tid = threadIdx.x;
    __shared__ float pl[96 * 60];

    #pragma unroll
    for (int i = 0; i < 21; ++i) {
        int e = tid + i * 256;            // 5376 = 96*56
        int ch = e / 56, mm = e - ch * 56;
        int m = cx * 56 + mm;
        int mh = m / 28, mw = m - mh * 28;
        const unsigned short* p = conv1 + ((size_t)(b * 128 + 32 + ch)) * HWN + mh * 112 + mw * 2;
        pl[ch * 60 + mm] = fmaxf(fmaxf(bf2f(p[0]), bf2f(p[1])),
                                 fmaxf(bf2f(p[56]), bf2f(p[57])));
    }
    __syncthreads();

    int cg = tid & 63;
    int cib = tid >> 6;
    float acc[8];
    #pragma unroll
    for (int i = 0; i < 8; ++i) acc[i] = 0.f;
    const float* pb = &pl[(32 + cg) * 60];
    for (int mm4 = 0; mm4 < 14; ++mm4) {
        float4 bv = *(const float4*)&pb[mm4 * 4];
        #pragma unroll
        for (int i = 0; i < 8; ++i) {
            float4 av = *(const float4*)&pl[(cib + 4 * i) * 60 + mm4 * 4];
            acc[i] = fmaf(av.x, bv.x, acc[i]);
            acc[i] = fmaf(av.y, bv.y, acc[i]);
            acc[i] = fmaf(av.z, bv.z, acc[i]);
            acc[i] = fmaf(av.w, bv.w, acc[i]);
        }
    }
    float* out = spart + ((size_t)(b * 14 + cx)) * 2048;
    #pragma unroll
    for (int i = 0; i < 8; ++i) out[tid + i * 256] = acc[i];
}

// ---------------- kernel 4: y = theta^T S / Np via MFMA + BN2 stats ----------------
// grid (49,B), 256 thr (4 waves). M=64 hw, N=64 cg, K=32 (single MFMA step).
// Tt rows padded to 40 shorts (80 B: b128-aligned, 2-way banks). y stored bf16.
__global__ __launch_bounds__(256) void k_y(const unsigned short* __restrict__ conv1,
                                           const float* __restrict__ spart,
                                           unsigned short* __restrict__ y,
                                           float* __restrict__ bn2acc) {
    int b = blockIdx.y;
    int hw0 = blockIdx.x * 64;
    int tid = threadIdx.x;
    int wv = tid >> 6, ln = tid & 63;
    int col = ln & 15, quad = ln >> 4;

    __shared__ unsigned short St[64 * 40];   // [cg][ci], padded
    __shared__ unsigned short Tt[64 * 40];   // [hw][ci], padded
    __shared__ float shs[64], shq[64];

    // reduce S partials -> St[cg][ci] bf16 (scaled by 1/Np)
    for (int id = tid; id < 2048; id += 256) {
        const float* p = spart + (size_t)b * 14 * 2048 + id;
        float s = 0.f;
        #pragma unroll
        for (int j = 0; j < 14; ++j) s += p[j * 2048];
        int ci = id >> 6, cg = id & 63;
        St[cg * 40 + ci] = f2bf(s * (1.0f / NPP));
    }
    // stage theta transposed: Tt[hw][ci]
    {
        int p2 = tid & 15, hwq = tid >> 4;
        int c0 = 2 * p2;
        const unsigned short* tb = conv1 + (size_t)(b * 128) * HWN + hw0 + hwq * 4;
        ushort4 v0 = *(const ushort4*)(tb + (size_t)c0 * HWN);
        ushort4 v1 = *(const ushort4*)(tb + (size_t)(c0 + 1) * HWN);
        unsigned int* tw = (unsigned int*)Tt;
        tw[(hwq * 4 + 0) * 20 + p2] = (unsigned)v0.x | ((unsigned)v1.x << 16);
        tw[(hwq * 4 + 1) * 20 + p2] = (unsigned)v0.y | ((unsigned)v1.y << 16);
        tw[(hwq * 4 + 2) * 20 + p2] = (unsigned)v0.z | ((unsigned)v1.z << 16);
        tw[(hwq * 4 + 3) * 20 + p2] = (unsigned)v0.w | ((unsigned)v1.w << 16);
    }
    if (tid < 64) { shs[tid] = 0.f; shq[tid] = 0.f; }
    __syncthreads();

    short8 af = *(const short8*)&Tt[(wv * 16 + col) * 40 + quad * 8];
    #pragma unroll
    for (int nt = 0; nt < 4; ++nt) {
        short8 bf = *(const short8*)&St[(nt * 16 + col) * 40 + quad * 8];
        floatx4 acc = (floatx4){0.f, 0.f, 0.f, 0.f};
        acc = __builtin_amdgcn_mfma_f32_16x16x32_bf16(af, bf, acc, 0, 0, 0);
        int cg = nt * 16 + col;
        int hw = hw0 + wv * 16 + quad * 4;
        ushort4 st;
        st.x = f2bf(acc[0]); st.y = f2bf(acc[1]);
        st.z = f2bf(acc[2]); st.w = f2bf(acc[3]);
        *(ushort4*)&y[((size_t)(b * NCG + cg)) * HWN + hw] = st;
        float s = acc[0] + acc[1] + acc[2] + acc[3];
        float q = acc[0] * acc[0] + acc[1] * acc[1] + acc[2] * acc[2] + acc[3] * acc[3];
        atomicAdd(&shs[cg], s);
        atomicAdd(&shq[cg], q);
    }
    __syncthreads();
    if (tid < 64) {
        atomicAdd(&bn2acc[tid], shs[tid]);
        atomicAdd(&bn2acc[64 + tid], shq[tid]);
    }
}

// ---------------- kernel 5: BN2+ReLU+conv1x1(z) + residual via MFMA ----------------
// grid (49,B), 256 thr. M=64 hw, N=256 co, K=64 (2 steps). Rows padded to 72 shorts.
__global__ __launch_bounds__(256) void k_convz(const unsigned short* __restrict__ y,
                                               const unsigned short* __restrict__ wzb,
                                               const float* __restrict__ bn2acc,
                                               const float* __restrict__ gamma,
                                               const float* __restrict__ beta,
                                               const float* __restrict__ b_z,
                                               const float* __restrict__ x,
                                               float* __restrict__ out) {
    int b = blockIdx.y;
    int hw0 = blockIdx.x * 64;
    int tid = threadIdx.x;
    int wv = tid >> 6, ln = tid & 63;
    int col = ln & 15, quad = ln >> 4;

    __shared__ unsigned short Wl[256 * 72];  // [co][k] padded image (DMA'd linearly)
    __shared__ unsigned short Yt[64 * 72];   // [hw][k] padded
    __shared__ float ab2_s[128];

    // W DMA: 36864 B = 36 instrs of 1 KB; 9 per wave; image pre-swizzled in k_prep
    #pragma unroll
    for (int i = 0; i < 9; ++i) {
        int j = wv * 9 + i;
        const unsigned short* gp = wzb + j * 512 + ln * 8;
        __builtin_amdgcn_global_load_lds(
            (const __attribute__((address_space(1))) unsigned int*)gp,
            (__attribute__((address_space(3))) unsigned int*)&Wl[j * 512],
            16, 0, 0);
    }
    if (tid < 64) {   // BN2 finalize
        const float inv = 1.0f / (BB * HWN);
        float mean = bn2acc[tid] * inv;
        float var  = bn2acc[64 + tid] * inv - mean * mean;
        float a = gamma[tid] * rsqrtf(var + 1e-5f);
        ab2_s[tid] = a;
        ab2_s[64 + tid] = beta[tid] - mean * a;
    }
    __syncthreads();   // ab2_s visible (also drains W DMA)

    // stage Y: BN2 affine + ReLU + transpose -> Yt[hw][k]
    {
        int p2 = tid & 15, hwq = tid >> 4;
        const unsigned short* ybase = y + (size_t)(b * NCG) * HWN + hw0 + hwq * 4;
        unsigned int* yw = (unsigned int*)Yt;
        #pragma unroll
        for (int h = 0; h < 2; ++h) {
            int k0 = h * 32 + 2 * p2;
            ushort4 v0 = *(const ushort4*)(ybase + (size_t)k0 * HWN);
            ushort4 v1 = *(const ushort4*)(ybase + (size_t)(k0 + 1) * HWN);
            float a0 = ab2_s[k0],     d0 = ab2_s[64 + k0];
            float a1 = ab2_s[k0 + 1], d1 = ab2_s[64 + k0 + 1];
            float r0[4] = { fmaxf(fmaf(a0, bf2f(v0.x), d0), 0.f), fmaxf(fmaf(a0, bf2f(v0.y), d0), 0.f),
                            fmaxf(fmaf(a0, bf2f(v0.z), d0), 0.f), fmaxf(fmaf(a0, bf2f(v0.w), d0), 0.f) };
            float r1[4] = { fmaxf(fmaf(a1, bf2f(v1.x), d1), 0.f), fmaxf(fmaf(a1, bf2f(v1.y), d1), 0.f),
                            fmaxf(fmaf(a1, bf2f(v1.z), d1), 0.f), fmaxf(fmaf(a1, bf2f(v1.w), d1), 0.f) };
            #pragma unroll
            for (int i = 0; i < 4; ++i) {
                unsigned int w = (unsigned int)f2bf(r0[i]) | ((unsigned int)f2bf(r1[i]) << 16);
                yw[(hwq * 4 + i) * 36 + h * 16 + p2] = w;
            }
        }
    }
    __syncthreads();

    floatx4 acc[16];
    #pragma unroll
    for (int nt = 0; nt < 16; ++nt) acc[nt] = (floatx4){0.f, 0.f, 0.f, 0.f};

    #pragma unroll
    for (int kk = 0; kk < 2; ++kk) {
        short8 af = *(const short8*)&Yt[(wv * 16 + col) * 72 + kk * 32 + quad * 8];
        #pragma unroll
        for (int nt = 0; nt < 16; ++nt) {
            short8 bf = *(const short8*)&Wl[(nt * 16 + col) * 72 + kk * 32 + quad * 8];
            acc[nt] = __builtin_amdgcn_mfma_f32_16x16x32_bf16(af, bf, acc[nt], 0, 0, 0);
        }
    }

    #pragma unroll
    for (int nt = 0; nt < 16; ++nt) {
        int co = nt * 16 + col;
        size_t base = ((size_t)(b * CC + co)) * HWN + hw0 + wv * 16 + quad * 4;
        float4 xv = *(const float4*)&x[base];
        float bz = b_z[co];
        float4 r = make_float4(acc[nt][0] + bz + xv.x, acc[nt][1] + bz + xv.y,
                               acc[nt][2] + bz + xv.z, acc[nt][3] + bz + xv.w);
        *(float4*)&out[base] = r;
    }
}

extern "C" void kernel_launch(void* const* d_in, const int* in_sizes, int n_in,
                              void* d_out, int out_size, void* d_ws, size_t ws_size,
                              hipStream_t stream) {
    (void)in_sizes; (void)n_in; (void)out_size; (void)ws_size;
    const float* x   = (const float*)d_in[0];
    const float* g1  = (const float*)d_in[1];
    const float* b1  = (const float*)d_in[2];
    const float* w_g = (const float*)d_in[3];
    const float* b_g = (const float*)d_in[4];
    const float* w_t = (const float*)d_in[5];
    const float* b_t = (const float*)d_in[6];
    const float* w_p = (const float*)d_in[7];
    const float* b_p = (const float*)d_in[8];
    const float* g2  = (const float*)d_in[9];
    const float* b2  = (const float*)d_in[10];
    const float* w_z = (const float*)d_in[11];
    const float* b_z = (const float*)d_in[12];
    float* out = (float*)d_out;

    float* ws     = (float*)d_ws;
    float* bn1acc = ws;                                    // 512
    float* bn2acc = ws + 512;                              // 128
    unsigned short* wcat  = (unsigned short*)(ws + 1024);  // 32768 shorts
    unsigned short* wzb   = (unsigned short*)(ws + 17408); // 256*72 shorts
    unsigned short* conv1 = (unsigned short*)(ws + 26624); // 16*128*3136 shorts
    float* spart  = ws + 3237888;                          // 16*14*2048
    unsigned short* yb    = (unsigned short*)(ws + 3696640); // 16*64*3136 shorts

    k_prep  <<<dim3(128),       dim3(256), 0, stream>>>(w_t, w_p, w_g, w_z, wcat, wzb, ws);
    k_bn1a  <<<dim3(BB * CC),   dim3(256), 0, stream>>>(x, bn1acc);
    k_conv1 <<<dim3(49, BB),    dim3(256), 0, stream>>>(x, wcat, bn1acc, g1, b1, b_g, b_t, b_p, conv1);
    k_spart <<<dim3(14, BB),    dim3(256), 0, stream>>>(conv1, spart);
    k_y     <<<dim3(49, BB),    dim3(256), 0, stream>>>(conv1, spart, yb, bn2acc);
    k_convz <<<dim3(49, BB),    dim3(256), 0, stream>>>(yb, wzb, bn2acc, g2, b2, b_z, x, out);
}

// Round 5
// 192.798 us; speedup vs baseline: 1.6380x; 1.0314x over previous
//
#include <hip/hip_runtime.h>
#include <hip/hip_bf16.h>

#define BB 16
#define CC 256
#define HWN 3136
#define NCG 64
#define NCI 32
#define NPP 784   // 28*28

typedef __attribute__((ext_vector_type(8))) short short8;
typedef __attribute__((ext_vector_type(4))) float floatx4;

__device__ __forceinline__ unsigned short f2bf(float f) {
    union { __hip_bfloat16 h; unsigned short u; } cv;
    cv.h = __float2bfloat16(f);
    return cv.u;
}
__device__ __forceinline__ float bf2f(unsigned short u) {
    return __uint_as_float(((unsigned)u) << 16);
}

// ---------------- kernel P: weights->bf16 (+swizzled w_z image) + zero accs/pads ----------------
__global__ __launch_bounds__(256) void k_prep(const float* __restrict__ w_t,
                                              const float* __restrict__ w_p,
                                              const float* __restrict__ w_g,
                                              const float* __restrict__ w_z,
                                              unsigned short* __restrict__ wcat,
                                              unsigned short* __restrict__ wzb,
                                              unsigned short* __restrict__ pool,
                                              float* __restrict__ accs) {
    int o = blockIdx.x;    // 0..127
    int c = threadIdx.x;   // 0..255
    const float* src = (o < 32) ? (w_t + o * CC)
                      : (o < 64) ? (w_p + (o - 32) * CC)
                                 : (w_g + (o - 64) * CC);
    wcat[o * CC + c] = f2bf(src[c]);
    {   // w_z: rows 2o, 2o+1 of padded [256][72] image
        int r = o * 2 + (c >> 7);
        int kk = c & 127;
        if (kk < 72)
            wzb[r * 72 + kk] = (kk < 64) ? f2bf(w_z[r * 64 + kk]) : (unsigned short)0;
    }
    if (o < 96) {   // zero pooled K-pad cols 784..799 for channel o, all 16 batches
        int b = c >> 4, kk = c & 15;
        pool[((size_t)(b * 96 + o)) * 800 + 784 + kk] = 0;
    }
    if (o == 0) {
        for (int i = c; i < 640; i += 256) accs[i] = 0.f;
    }
}

// ---------------- kernel 1: BN1 partial sums (one block per (b,c)) ----------------
__global__ __launch_bounds__(256) void k_bn1a(const float* __restrict__ x,
                                              float* __restrict__ acc) {
    int blk = blockIdx.x;           // b*CC + c
    int c = blk & (CC - 1);
    const float4* p = (const float4*)(x + (size_t)blk * HWN);
    int tid = threadIdx.x;
    float s = 0.f, q = 0.f;
    #pragma unroll
    for (int i = tid; i < 784; i += 256) {
        float4 v = p[i];
        s += v.x + v.y + v.z + v.w;
        q += v.x * v.x + v.y * v.y + v.z * v.z + v.w * v.w;
    }
    #pragma unroll
    for (int off = 32; off > 0; off >>= 1) {
        s += __shfl_down(s, off);
        q += __shfl_down(q, off);
    }
    __shared__ float sh[8];
    int wid = tid >> 6, lane = tid & 63;
    if (lane == 0) { sh[wid] = s; sh[4 + wid] = q; }
    __syncthreads();
    if (tid == 0) {
        atomicAdd(&acc[c], sh[0] + sh[1] + sh[2] + sh[3]);
        atomicAdd(&acc[CC + c], sh[4] + sh[5] + sh[6] + sh[7]);
    }
}

// ---------------- kernel 2: BN1+ReLU+conv1x1 MFMA, fused maxpool ----------------
// grid (28,B); 256 thr. M=128 o x N=112 hw (exactly image rows 2bx,2bx+1); K=256.
// Outputs: th[b][32][HWN] full-res theta (bf16), pool[b][96][800] pooled phi|g (bf16).
__global__ __launch_bounds__(256) void k_conv1(const float* __restrict__ x,
                                               const unsigned short* __restrict__ wcat,
                                               const float* __restrict__ bn1acc,
                                               const float* __restrict__ gamma,
                                               const float* __restrict__ beta,
                                               const float* __restrict__ b_g,
                                               const float* __restrict__ b_t,
                                               const float* __restrict__ b_p,
                                               unsigned short* __restrict__ th,
                                               unsigned short* __restrict__ pool) {
    int b  = blockIdx.y;
    int bx = blockIdx.x;           // 0..27
    int hw0 = bx * 112;
    int tid = threadIdx.x;
    int wv = tid >> 6, ln = tid & 63;
    int col = ln & 15, quad = ln >> 4;

    __shared__ unsigned short smem[128 * 120];   // A[0..4095]|B[4096..7679]; later Ct[128][120]
    unsigned short* As = smem;
    unsigned short* Bs = smem + 4096;
    __shared__ float ab_s[512];
    __shared__ float bias_s[128];

    {   // fold BN1 finalize
        const float inv = 1.0f / (BB * HWN);
        float mean = bn1acc[tid] * inv;
        float var  = bn1acc[CC + tid] * inv - mean * mean;
        float a = gamma[tid] * rsqrtf(var + 1e-5f);
        ab_s[tid] = a;
        ab_s[CC + tid] = beta[tid] - mean * a;
    }
    if (tid < 128) {
        int o = tid;
        bias_s[o] = (o < 32) ? b_t[o] : (o < 64) ? b_p[o - 32] : b_g[o - 64];
    }
    __syncthreads();

    floatx4 acc[2][7];
    #pragma unroll
    for (int mt = 0; mt < 2; ++mt)
        for (int nt = 0; nt < 7; ++nt)
            acc[mt][nt] = (floatx4){0.f, 0.f, 0.f, 0.f};

    int p   = tid & 15;    // c-pair index
    int hwq = tid >> 4;    // base hw-quad
    const float* xb = x + (size_t)(b * CC) * HWN + hw0;

    for (int k0 = 0; k0 < CC; k0 += 32) {
        // stage A (weights) via async global->LDS
        #pragma unroll
        for (int i = 0; i < 2; ++i) {
            int row = wv * 32 + i * 16 + (ln >> 2);
            int q   = ln & 3;
            const unsigned short* gp = wcat + row * CC + k0 + q * 8;
            __builtin_amdgcn_global_load_lds(
                (const __attribute__((address_space(1))) unsigned int*)gp,
                (__attribute__((address_space(3))) unsigned int*)&As[(wv * 2 + i) * 512],
                16, 0, 0);
        }
        // stage B: x -> BN+ReLU -> bf16 [hw][k]
        {
            int c0 = k0 + 2 * p;
            float a0 = ab_s[c0],     d0 = ab_s[CC + c0];
            float a1 = ab_s[c0 + 1], d1 = ab_s[CC + c0 + 1];
            unsigned int* bw = (unsigned int*)Bs;
            #pragma unroll
            for (int t = 0; t < 2; ++t) {
                int qi = hwq + 16 * t;
                if (qi < 28) {
                    float4 v0 = *(const float4*)(xb + (size_t)c0 * HWN + qi * 4);
                    float4 v1 = *(const float4*)(xb + (size_t)(c0 + 1) * HWN + qi * 4);
                    float r0[4] = { fmaxf(fmaf(a0, v0.x, d0), 0.f), fmaxf(fmaf(a0, v0.y, d0), 0.f),
                                    fmaxf(fmaf(a0, v0.z, d0), 0.f), fmaxf(fmaf(a0, v0.w, d0), 0.f) };
                    float r1[4] = { fmaxf(fmaf(a1, v1.x, d1), 0.f), fmaxf(fmaf(a1, v1.y, d1), 0.f),
                                    fmaxf(fmaf(a1, v1.z, d1), 0.f), fmaxf(fmaf(a1, v1.w, d1), 0.f) };
                    #pragma unroll
                    for (int i = 0; i < 4; ++i) {
                        unsigned int w = (unsigned int)f2bf(r0[i]) | ((unsigned int)f2bf(r1[i]) << 16);
                        bw[(qi * 4 + i) * 16 + p] = w;
                    }
                }
            }
        }
        __syncthreads();

        short8 af0 = *(const short8*)&As[(wv * 32 +      col) * 32 + quad * 8];
        short8 af1 = *(const short8*)&As[(wv * 32 + 16 + col) * 32 + quad * 8];
        #pragma unroll
        for (int nt = 0; nt < 7; ++nt) {
            short8 bf = *(const short8*)&Bs[(nt * 16 + col) * 32 + quad * 8];
            acc[0][nt] = __builtin_amdgcn_mfma_f32_16x16x32_bf16(af0, bf, acc[0][nt], 0, 0, 0);
            acc[1][nt] = __builtin_amdgcn_mfma_f32_16x16x32_bf16(af1, bf, acc[1][nt], 0, 0, 0);
        }
        __syncthreads();
    }

    // ---- stage C (with bias) to LDS, overlaying A/B ----
    unsigned short* Ct = smem;    // [128][120]
    #pragma unroll
    for (int mt = 0; mt < 2; ++mt) {
        int obase = wv * 32 + mt * 16 + quad * 4;
        #pragma unroll
        for (int r = 0; r < 4; ++r) {
            float bias = bias_s[obase + r];
            #pragma unroll
            for (int nt = 0; nt < 7; ++nt)
                Ct[(obase + r) * 120 + nt * 16 + col] = f2bf(acc[mt][nt][r] + bias);
        }
    }
    __syncthreads();

    // ---- theta (ch 0..31): full-res vectorized store ----
    #pragma unroll
    for (int i = 0; i < 4; ++i) {
        int e = tid + i * 256;     // 896 = 32ch x 28 col4
        if (e < 896) {
            int ch = e / 28, c4 = e - ch * 28;
            ushort4 v = *(const ushort4*)&Ct[ch * 120 + c4 * 4];
            *(ushort4*)&th[((size_t)(b * NCI + ch)) * HWN + hw0 + c4 * 4] = v;
        }
    }
    // ---- phi/g (ch 32..127): 2x2 maxpool -> pool[b][ch-32][bx*28 + m] ----
    #pragma unroll
    for (int i = 0; i < 11; ++i) {
        int e = tid + i * 256;     // 2688 = 96ch x 28 m
        if (e < 2688) {
            int ch = e / 28, m = e - ch * 28;
            const unsigned short* r0p = &Ct[(32 + ch) * 120 + 2 * m];
            float v = fmaxf(fmaxf(bf2f(r0p[0]), bf2f(r0p[1])),
                            fmaxf(bf2f(r0p[56]), bf2f(r0p[57])));
            pool[((size_t)(b * 96 + ch)) * 800 + bx * 28 + m] = f2bf(v);
        }
    }
}

// ---------------- kernel 3: S = g_p . phi_p^T / Np via MFMA ----------------
// grid (16); 256 thr; waves split K (800 = 25 steps of 32), direct global frag loads.
// Output Sg[b][cg][ci] bf16, rows padded to 40 (k_y's St layout, pre-scaled).
__global__ __launch_bounds__(256) void k_sgemm(const unsigned short* __restrict__ pool,
                                               unsigned short* __restrict__ Sg) {
    int b = blockIdx.x;
    int tid = threadIdx.x;
    int wv = tid >> 6, ln = tid & 63;
    int col = ln & 15, quad = ln >> 4;
    __shared__ float Sred[4 * 2048];

    const unsigned short* gbase = pool + ((size_t)(b * 96 + 32)) * 800;  // g rows (cg)
    const unsigned short* pbase = pool + ((size_t)(b * 96)) * 800;       // phi rows (ci)

    floatx4 acc[4][2];
    #pragma unroll
    for (int mt = 0; mt < 4; ++mt)
        for (int nt = 0; nt < 2; ++nt)
            acc[mt][nt] = (floatx4){0.f, 0.f, 0.f, 0.f};

    for (int s = wv; s < 25; s += 4) {
        int k0 = s * 32;
        short8 af[4], bfr[2];
        #pragma unroll
        for (int mt = 0; mt < 4; ++mt)
            af[mt] = *(const short8*)&gbase[(mt * 16 + col) * 800 + k0 + quad * 8];
        #pragma unroll
        for (int nt = 0; nt < 2; ++nt)
            bfr[nt] = *(const short8*)&pbase[(nt * 16 + col) * 800 + k0 + quad * 8];
        #pragma unroll
        for (int mt = 0; mt < 4; ++mt)
            #pragma unroll
            for (int nt = 0; nt < 2; ++nt)
                acc[mt][nt] = __builtin_amdgcn_mfma_f32_16x16x32_bf16(af[mt], bfr[nt], acc[mt][nt], 0, 0, 0);
    }
    #pragma unroll
    for (int mt = 0; mt < 4; ++mt)
        for (int nt = 0; nt < 2; ++nt)
            for (int r = 0; r < 4; ++r) {
                int cg = mt * 16 + quad * 4 + r;
                int ci = nt * 16 + col;
                Sred[wv * 2048 + cg * 32 + ci] = acc[mt][nt][r];
            }
    __syncthreads();
    #pragma unroll
    for (int j = 0; j < 8; ++j) {
        int idx = tid + j * 256;
        float s = Sred[idx] + Sred[2048 + idx] + Sred[4096 + idx] + Sred[6144 + idx];
        int cg = idx >> 5, ci = idx & 31;
        Sg[(size_t)b * 2560 + cg * 40 + ci] = f2bf(s * (1.0f / NPP));
    }
}

// ---------------- kernel 4: y = theta^T S via MFMA + BN2 stats ----------------
__global__ __launch_bounds__(256) void k_y(const unsigned short* __restrict__ th,
                                           const unsigned short* __restrict__ Sg,
                                           unsigned short* __restrict__ y,
                                           float* __restrict__ bn2acc) {
    int b = blockIdx.y;
    int hw0 = blockIdx.x * 64;
    int tid = threadIdx.x;
    int wv = tid >> 6, ln = tid & 63;
    int col = ln & 15, quad = ln >> 4;

    __shared__ unsigned short St[64 * 40];   // [cg][ci], padded
    __shared__ unsigned short Tt[64 * 40];   // [hw][ci], padded
    __shared__ float shs[64], shq[64];

    {   // flat copy of pre-scaled S
        const unsigned int* sgw = (const unsigned int*)(Sg + (size_t)b * 2560);
        unsigned int* stw = (unsigned int*)St;
        for (int i = tid; i < 1280; i += 256) stw[i] = sgw[i];
    }
    {   // stage theta transposed: Tt[hw][ci]
        int p2 = tid & 15, hwq = tid >> 4;
        int c0 = 2 * p2;
        const unsigned short* tb = th + (size_t)(b * NCI) * HWN + hw0 + hwq * 4;
        ushort4 v0 = *(const ushort4*)(tb + (size_t)c0 * HWN);
        ushort4 v1 = *(const ushort4*)(tb + (size_t)(c0 + 1) * HWN);
        unsigned int* tw = (unsigned int*)Tt;
        tw[(hwq * 4 + 0) * 20 + p2] = (unsigned)v0.x | ((unsigned)v1.x << 16);
        tw[(hwq * 4 + 1) * 20 + p2] = (unsigned)v0.y | ((unsigned)v1.y << 16);
        tw[(hwq * 4 + 2) * 20 + p2] = (unsigned)v0.z | ((unsigned)v1.z << 16);
        tw[(hwq * 4 + 3) * 20 + p2] = (unsigned)v0.w | ((unsigned)v1.w << 16);
    }
    if (tid < 64) { shs[tid] = 0.f; shq[tid] = 0.f; }
    __syncthreads();

    short8 af = *(const short8*)&Tt[(wv * 16 + col) * 40 + quad * 8];
    #pragma unroll
    for (int nt = 0; nt < 4; ++nt) {
        short8 bf = *(const short8*)&St[(nt * 16 + col) * 40 + quad * 8];
        floatx4 acc = (floatx4){0.f, 0.f, 0.f, 0.f};
        acc = __builtin_amdgcn_mfma_f32_16x16x32_bf16(af, bf, acc, 0, 0, 0);
        int cg = nt * 16 + col;
        int hw = hw0 + wv * 16 + quad * 4;
        ushort4 st;
        st.x = f2bf(acc[0]); st.y = f2bf(acc[1]);
        st.z = f2bf(acc[2]); st.w = f2bf(acc[3]);
        *(ushort4*)&y[((size_t)(b * NCG + cg)) * HWN + hw] = st;
        float s = acc[0] + acc[1] + acc[2] + acc[3];
        float q = acc[0] * acc[0] + acc[1] * acc[1] + acc[2] * acc[2] + acc[3] * acc[3];
        atomicAdd(&shs[cg], s);
        atomicAdd(&shq[cg], q);
    }
    __syncthreads();
    if (tid < 64) {
        atomicAdd(&bn2acc[tid], shs[tid]);
        atomicAdd(&bn2acc[64 + tid], shq[tid]);
    }
}

// ---------------- kernel 5: BN2+ReLU+conv1x1(z) + residual via MFMA ----------------
__global__ __launch_bounds__(256) void k_convz(const unsigned short* __restrict__ y,
                                               const unsigned short* __restrict__ wzb,
                                               const float* __restrict__ bn2acc,
                                               const float* __restrict__ gamma,
                                               const float* __restrict__ beta,
                                               const float* __restrict__ b_z,
                                               const float* __restrict__ x,
                                               float* __restrict__ out) {
    int b = blockIdx.y;
    int hw0 = blockIdx.x * 64;
    int tid = threadIdx.x;
    int wv = tid >> 6, ln = tid & 63;
    int col = ln & 15, quad = ln >> 4;

    __shared__ unsigned short Wl[256 * 72];
    __shared__ unsigned short Yt[64 * 72];
    __shared__ float ab2_s[128];

    #pragma unroll
    for (int i = 0; i < 9; ++i) {
        int j = wv * 9 + i;
        const unsigned short* gp = wzb + j * 512 + ln * 8;
        __builtin_amdgcn_global_load_lds(
            (const __attribute__((address_space(1))) unsigned int*)gp,
            (__attribute__((address_space(3))) unsigned int*)&Wl[j * 512],
            16, 0, 0);
    }
    if (tid < 64) {
        const float inv = 1.0f / (BB * HWN);
        float mean = bn2acc[tid] * inv;
        float var  = bn2acc[64 + tid] * inv - mean * mean;
        float a = gamma[tid] * rsqrtf(var + 1e-5f);
        ab2_s[tid] = a;
        ab2_s[64 + tid] = beta[tid] - mean * a;
    }
    __syncthreads();

    {
        int p2 = tid & 15, hwq = tid >> 4;
        const unsigned short* ybase = y + (size_t)(b * NCG) * HWN + hw0 + hwq * 4;
        unsigned int* yw = (unsigned int*)Yt;
        #pragma unroll
        for (int h = 0; h < 2; ++h) {
            int k0 = h * 32 + 2 * p2;
            ushort4 v0 = *(const ushort4*)(ybase + (size_t)k0 * HWN);
            ushort4 v1 = *(const ushort4*)(ybase + (size_t)(k0 + 1) * HWN);
            float a0 = ab2_s[k0],     d0 = ab2_s[64 + k0];
            float a1 = ab2_s[k0 + 1], d1 = ab2_s[64 + k0 + 1];
            float r0[4] = { fmaxf(fmaf(a0, bf2f(v0.x), d0), 0.f), fmaxf(fmaf(a0, bf2f(v0.y), d0), 0.f),
                            fmaxf(fmaf(a0, bf2f(v0.z), d0), 0.f), fmaxf(fmaf(a0, bf2f(v0.w), d0), 0.f) };
            float r1[4] = { fmaxf(fmaf(a1, bf2f(v1.x), d1), 0.f), fmaxf(fmaf(a1, bf2f(v1.y), d1), 0.f),
                            fmaxf(fmaf(a1, bf2f(v1.z), d1), 0.f), fmaxf(fmaf(a1, bf2f(v1.w), d1), 0.f) };
            #pragma unroll
            for (int i = 0; i < 4; ++i) {
                unsigned int w = (unsigned int)f2bf(r0[i]) | ((unsigned int)f2bf(r1[i]) << 16);
                yw[(hwq * 4 + i) * 36 + h * 16 + p2] = w;
            }
        }
    }
    __syncthreads();

    floatx4 acc[16];
    #pragma unroll
    for (int nt = 0; nt < 16; ++nt) acc[nt] = (floatx4){0.f, 0.f, 0.f, 0.f};

    #pragma unroll
    for (int kk = 0; kk < 2; ++kk) {
        short8 af = *(const short8*)&Yt[(wv * 16 + col) * 72 + kk * 32 + quad * 8];
        #pragma unroll
        for (int nt = 0; nt < 16; ++nt) {
            short8 bf = *(const short8*)&Wl[(nt * 16 + col) * 72 + kk * 32 + quad * 8];
            acc[nt] = __builtin_amdgcn_mfma_f32_16x16x32_bf16(af, bf, acc[nt], 0, 0, 0);
        }
    }

    #pragma unroll
    for (int nt = 0; nt < 16; ++nt) {
        int co = nt * 16 + col;
        size_t base = ((size_t)(b * CC + co)) * HWN + hw0 + wv * 16 + quad * 4;
        float4 xv = *(const float4*)&x[base];
        float bz = b_z[co];
        float4 r = make_float4(acc[nt][0] + bz + xv.x, acc[nt][1] + bz + xv.y,
                               acc[nt][2] + bz + xv.z, acc[nt][3] + bz + xv.w);
        *(float4*)&out[base] = r;
    }
}

extern "C" void kernel_launch(void* const* d_in, const int* in_sizes, int n_in,
                              void* d_out, int out_size, void* d_ws, size_t ws_size,
                              hipStream_t stream) {
    (void)in_sizes; (void)n_in; (void)out_size; (void)ws_size;
    const float* x   = (const float*)d_in[0];
    const float* g1  = (const float*)d_in[1];
    const float* b1  = (const float*)d_in[2];
    const float* w_g = (const float*)d_in[3];
    const float* b_g = (const float*)d_in[4];
    const float* w_t = (const float*)d_in[5];
    const float* b_t = (const float*)d_in[6];
    const float* w_p = (const float*)d_in[7];
    const float* b_p = (const float*)d_in[8];
    const float* g2  = (const float*)d_in[9];
    const float* b2  = (const float*)d_in[10];
    const float* w_z = (const float*)d_in[11];
    const float* b_z = (const float*)d_in[12];
    float* out = (float*)d_out;

    float* ws     = (float*)d_ws;
    float* bn1acc = ws;                                      // 512
    float* bn2acc = ws + 512;                                // 128
    unsigned short* wcat  = (unsigned short*)(ws + 1024);    // 32768 shorts
    unsigned short* wzb   = (unsigned short*)(ws + 17408);   // 18432 shorts
    unsigned short* th    = (unsigned short*)(ws + 26624);   // 16*32*3136 shorts
    unsigned short* pool  = (unsigned short*)(ws + 829440);  // 16*96*800 shorts
    unsigned short* Sg    = (unsigned short*)(ws + 1443840); // 16*64*40 shorts
    unsigned short* yb    = (unsigned short*)(ws + 1464320); // 16*64*3136 shorts

    k_prep  <<<dim3(128),     dim3(256), 0, stream>>>(w_t, w_p, w_g, w_z, wcat, wzb, pool, ws);
    k_bn1a  <<<dim3(BB * CC), dim3(256), 0, stream>>>(x, bn1acc);
    k_conv1 <<<dim3(28, BB),  dim3(256), 0, stream>>>(x, wcat, bn1acc, g1, b1, b_g, b_t, b_p, th, pool);
    k_sgemm <<<dim3(BB),      dim3(256), 0, stream>>>(pool, Sg);
    k_y     <<<dim3(49, BB),  dim3(256), 0, stream>>>(th, Sg, yb, bn2acc);
    k_convz <<<dim3(49, BB),  dim3(256), 0, stream>>>(yb, wzb, bn2acc, g2, b2, b_z, x, out);
}

// Round 6
// 173.788 us; speedup vs baseline: 1.8172x; 1.1094x over previous
//
#include <hip/hip_runtime.h>
#include <hip/hip_bf16.h>

#define BB 16
#define CC 256
#define HWN 3136
#define NCG 64
#define NCI 32
#define NPP 784   // 28*28

typedef __attribute__((ext_vector_type(8))) short short8;
typedef __attribute__((ext_vector_type(4))) float floatx4;

__device__ __forceinline__ unsigned short f2bf(float f) {
    union { __hip_bfloat16 h; unsigned short u; } cv;
    cv.h = __float2bfloat16(f);
    return cv.u;
}
__device__ __forceinline__ float bf2f(unsigned short u) {
    return __uint_as_float(((unsigned)u) << 16);
}

// ---------------- kernel P: weights->bf16 (+swizzled w_z image) + zero accs/pads ----------------
__global__ __launch_bounds__(256) void k_prep(const float* __restrict__ w_t,
                                              const float* __restrict__ w_p,
                                              const float* __restrict__ w_g,
                                              const float* __restrict__ w_z,
                                              unsigned short* __restrict__ wcat,
                                              unsigned short* __restrict__ wzb,
                                              unsigned short* __restrict__ pool,
                                              float* __restrict__ accs) {
    int o = blockIdx.x;    // 0..127
    int c = threadIdx.x;   // 0..255
    const float* src = (o < 32) ? (w_t + o * CC)
                      : (o < 64) ? (w_p + (o - 32) * CC)
                                 : (w_g + (o - 64) * CC);
    wcat[o * CC + c] = f2bf(src[c]);
    {   // w_z: rows 2o, 2o+1 of padded [256][72] image
        int r = o * 2 + (c >> 7);
        int kk = c & 127;
        if (kk < 72)
            wzb[r * 72 + kk] = (kk < 64) ? f2bf(w_z[r * 64 + kk]) : (unsigned short)0;
    }
    if (o < 96) {   // zero pooled K-pad cols 784..799 for channel o, all 16 batches
        int b = c >> 4, kk = c & 15;
        pool[((size_t)(b * 96 + o)) * 800 + 784 + kk] = 0;
    }
    if (o == 0) {   // zero bn1acc(512) + bn2acc(128) + T1(512) = 1152 floats
        for (int i = c; i < 1152; i += 256) accs[i] = 0.f;
    }
}

// ---------------- kernel 1: BN1 partial sums (one block per (b,c)) ----------------
__global__ __launch_bounds__(256) void k_bn1a(const float* __restrict__ x,
                                              float* __restrict__ acc) {
    int blk = blockIdx.x;           // b*CC + c
    int c = blk & (CC - 1);
    const float4* p = (const float4*)(x + (size_t)blk * HWN);
    int tid = threadIdx.x;
    float s = 0.f, q = 0.f;
    #pragma unroll
    for (int i = tid; i < 784; i += 256) {
        float4 v = p[i];
        s += v.x + v.y + v.z + v.w;
        q += v.x * v.x + v.y * v.y + v.z * v.z + v.w * v.w;
    }
    #pragma unroll
    for (int off = 32; off > 0; off >>= 1) {
        s += __shfl_down(s, off);
        q += __shfl_down(q, off);
    }
    __shared__ float sh[8];
    int wid = tid >> 6, lane = tid & 63;
    if (lane == 0) { sh[wid] = s; sh[4 + wid] = q; }
    __syncthreads();
    if (tid == 0) {
        atomicAdd(&acc[c], sh[0] + sh[1] + sh[2] + sh[3]);
        atomicAdd(&acc[CC + c], sh[4] + sh[5] + sh[6] + sh[7]);
    }
}

// ---------------- kernel 2: BN1+ReLU+conv1x1 MFMA, fused maxpool + T1 ----------------
// grid (28,B); 256 thr. M=128 o x N=112 hw; K=256, x prefetched one k-step ahead.
__global__ __launch_bounds__(256) void k_conv1(const float* __restrict__ x,
                                               const unsigned short* __restrict__ wcat,
                                               const float* __restrict__ bn1acc,
                                               const float* __restrict__ gamma,
                                               const float* __restrict__ beta,
                                               const float* __restrict__ b_g,
                                               const float* __restrict__ b_t,
                                               const float* __restrict__ b_p,
                                               unsigned short* __restrict__ th,
                                               unsigned short* __restrict__ pool,
                                               float* __restrict__ T1g) {
    int b  = blockIdx.y;
    int bx = blockIdx.x;           // 0..27
    int hw0 = bx * 112;
    int tid = threadIdx.x;
    int wv = tid >> 6, ln = tid & 63;
    int col = ln & 15, quad = ln >> 4;

    __shared__ unsigned short smem[128 * 120];   // A|B during K-loop; Ct afterwards
    unsigned short* As = smem;
    unsigned short* Bs = smem + 4096;
    __shared__ float ab_s[512];
    __shared__ float bias_s[128];

    {   // fold BN1 finalize
        const float inv = 1.0f / (BB * HWN);
        float mean = bn1acc[tid] * inv;
        float var  = bn1acc[CC + tid] * inv - mean * mean;
        float a = gamma[tid] * rsqrtf(var + 1e-5f);
        ab_s[tid] = a;
        ab_s[CC + tid] = beta[tid] - mean * a;
    }
    if (tid < 128) {
        int o = tid;
        bias_s[o] = (o < 32) ? b_t[o] : (o < 64) ? b_p[o - 32] : b_g[o - 64];
    }
    __syncthreads();

    floatx4 acc[2][7];
    #pragma unroll
    for (int mt = 0; mt < 2; ++mt)
        for (int nt = 0; nt < 7; ++nt)
            acc[mt][nt] = (floatx4){0.f, 0.f, 0.f, 0.f};

    int p   = tid & 15;    // c-pair index
    int hwq = tid >> 4;    // base hw-quad (0..15)
    const float* xb = x + (size_t)(b * CC) * HWN + hw0;
    bool q1 = (hwq + 16) < 28;

    // prefetch k0=0
    float4 pv0[2], pv1[2];
    {
        int c0 = 2 * p;
        pv0[0] = *(const float4*)(xb + (size_t)c0 * HWN + hwq * 4);
        pv1[0] = *(const float4*)(xb + (size_t)(c0 + 1) * HWN + hwq * 4);
        if (q1) {
            pv0[1] = *(const float4*)(xb + (size_t)c0 * HWN + (hwq + 16) * 4);
            pv1[1] = *(const float4*)(xb + (size_t)(c0 + 1) * HWN + (hwq + 16) * 4);
        }
    }

    for (int k0 = 0; k0 < CC; k0 += 32) {
        // stage A (weights) via async global->LDS
        #pragma unroll
        for (int i = 0; i < 2; ++i) {
            int row = wv * 32 + i * 16 + (ln >> 2);
            int q   = ln & 3;
            const unsigned short* gp = wcat + row * CC + k0 + q * 8;
            __builtin_amdgcn_global_load_lds(
                (const __attribute__((address_space(1))) unsigned int*)gp,
                (__attribute__((address_space(3))) unsigned int*)&As[(wv * 2 + i) * 512],
                16, 0, 0);
        }
        // stage B from prefetched regs
        {
            int c0 = k0 + 2 * p;
            float a0 = ab_s[c0],     d0 = ab_s[CC + c0];
            float a1 = ab_s[c0 + 1], d1 = ab_s[CC + c0 + 1];
            unsigned int* bw = (unsigned int*)Bs;
            #pragma unroll
            for (int t = 0; t < 2; ++t) {
                if (t == 0 || q1) {
                    int qi = hwq + 16 * t;
                    float4 v0 = pv0[t], v1 = pv1[t];
                    float r0[4] = { fmaxf(fmaf(a0, v0.x, d0), 0.f), fmaxf(fmaf(a0, v0.y, d0), 0.f),
                                    fmaxf(fmaf(a0, v0.z, d0), 0.f), fmaxf(fmaf(a0, v0.w, d0), 0.f) };
                    float r1[4] = { fmaxf(fmaf(a1, v1.x, d1), 0.f), fmaxf(fmaf(a1, v1.y, d1), 0.f),
                                    fmaxf(fmaf(a1, v1.z, d1), 0.f), fmaxf(fmaf(a1, v1.w, d1), 0.f) };
                    #pragma unroll
                    for (int i = 0; i < 4; ++i) {
                        unsigned int w = (unsigned int)f2bf(r0[i]) | ((unsigned int)f2bf(r1[i]) << 16);
                        bw[(qi * 4 + i) * 16 + p] = w;
                    }
                }
            }
        }
        // prefetch next k-step's x
        if (k0 + 32 < CC) {
            int c0 = k0 + 32 + 2 * p;
            pv0[0] = *(const float4*)(xb + (size_t)c0 * HWN + hwq * 4);
            pv1[0] = *(const float4*)(xb + (size_t)(c0 + 1) * HWN + hwq * 4);
            if (q1) {
                pv0[1] = *(const float4*)(xb + (size_t)c0 * HWN + (hwq + 16) * 4);
                pv1[1] = *(const float4*)(xb + (size_t)(c0 + 1) * HWN + (hwq + 16) * 4);
            }
        }
        __syncthreads();

        short8 af0 = *(const short8*)&As[(wv * 32 +      col) * 32 + quad * 8];
        short8 af1 = *(const short8*)&As[(wv * 32 + 16 + col) * 32 + quad * 8];
        #pragma unroll
        for (int nt = 0; nt < 7; ++nt) {
            short8 bf = *(const short8*)&Bs[(nt * 16 + col) * 32 + quad * 8];
            acc[0][nt] = __builtin_amdgcn_mfma_f32_16x16x32_bf16(af0, bf, acc[0][nt], 0, 0, 0);
            acc[1][nt] = __builtin_amdgcn_mfma_f32_16x16x32_bf16(af1, bf, acc[1][nt], 0, 0, 0);
        }
        __syncthreads();
    }

    // ---- stage C (with bias) to LDS ----
    unsigned short* Ct = smem;    // [128][120]
    #pragma unroll
    for (int mt = 0; mt < 2; ++mt) {
        int obase = wv * 32 + mt * 16 + quad * 4;
        #pragma unroll
        for (int r = 0; r < 4; ++r) {
            float bias = bias_s[obase + r];
            #pragma unroll
            for (int nt = 0; nt < 7; ++nt)
                Ct[(obase + r) * 120 + nt * 16 + col] = f2bf(acc[mt][nt][r] + bias);
        }
    }
    __syncthreads();

    // ---- theta (ch 0..31): full-res vectorized store ----
    #pragma unroll
    for (int i = 0; i < 4; ++i) {
        int e = tid + i * 256;     // 896 = 32ch x 28 col4
        if (e < 896) {
            int ch = e / 28, c4 = e - ch * 28;
            ushort4 v = *(const ushort4*)&Ct[ch * 120 + c4 * 4];
            *(ushort4*)&th[((size_t)(b * NCI + ch)) * HWN + hw0 + c4 * 4] = v;
        }
    }
    // ---- T1: per-batch theta row sums ----
    {
        int row = tid >> 3;      // 0..31
        int seg = tid & 7;       // 0..7
        float s = 0.f;
        #pragma unroll
        for (int j = 0; j < 14; ++j) s += bf2f(Ct[row * 120 + seg * 14 + j]);
        s += __shfl_down(s, 4);
        s += __shfl_down(s, 2);
        s += __shfl_down(s, 1);
        if (seg == 0) atomicAdd(&T1g[b * NCI + row], s);
    }
    // ---- phi/g (ch 32..127): 2x2 maxpool -> pool[b][ch-32][bx*28 + m] ----
    #pragma unroll
    for (int i = 0; i < 11; ++i) {
        int e = tid + i * 256;     // 2688 = 96ch x 28 m
        if (e < 2688) {
            int ch = e / 28, m = e - ch * 28;
            const unsigned short* r0p = &Ct[(32 + ch) * 120 + 2 * m];
            float v = fmaxf(fmaxf(bf2f(r0p[0]), bf2f(r0p[1])),
                            fmaxf(bf2f(r0p[56]), bf2f(r0p[57])));
            pool[((size_t)(b * 96 + ch)) * 800 + bx * 28 + m] = f2bf(v);
        }
    }
}

// ---------------- kernel 3: S = g.phi^T/Np (waves 0-3) + Gram/BN2 stats (waves 4-7) ----------------
// grid (16); 512 thr. Emits Sg (bf16, [cg][ci] rows 40, pre-scaled) and complete bn2acc.
__global__ __launch_bounds__(512) void k_sgemm(const unsigned short* __restrict__ pool,
                                               const unsigned short* __restrict__ th,
                                               const float* __restrict__ T1g,
                                               unsigned short* __restrict__ Sg,
                                               float* __restrict__ bn2acc) {
    int b = blockIdx.x;
    int tid = threadIdx.x;
    int wv = tid >> 6, ln = tid & 63;
    int col = ln & 15, quad = ln >> 4;
    __shared__ float Sred[4 * 2048];
    __shared__ float Gred[4 * 1024];
    __shared__ float T1s[32];
    __shared__ float shs[64], shq[64];

    if (tid < 64) { shs[tid] = 0.f; shq[tid] = 0.f; }
    if (tid < 32) T1s[tid] = T1g[b * NCI + tid];

    if (wv < 4) {
        const unsigned short* gbase = pool + ((size_t)(b * 96 + 32)) * 800;  // g rows (cg)
        const unsigned short* pbase = pool + ((size_t)(b * 96)) * 800;       // phi rows (ci)
        floatx4 acc[4][2];
        #pragma unroll
        for (int mt = 0; mt < 4; ++mt)
            for (int nt = 0; nt < 2; ++nt)
                acc[mt][nt] = (floatx4){0.f, 0.f, 0.f, 0.f};
        for (int s = wv; s < 25; s += 4) {
            int k0 = s * 32;
            short8 af[4], bfr[2];
            #pragma unroll
            for (int mt = 0; mt < 4; ++mt)
                af[mt] = *(const short8*)&gbase[(mt * 16 + col) * 800 + k0 + quad * 8];
            #pragma unroll
            for (int nt = 0; nt < 2; ++nt)
                bfr[nt] = *(const short8*)&pbase[(nt * 16 + col) * 800 + k0 + quad * 8];
            #pragma unroll
            for (int mt = 0; mt < 4; ++mt)
                #pragma unroll
                for (int nt = 0; nt < 2; ++nt)
                    acc[mt][nt] = __builtin_amdgcn_mfma_f32_16x16x32_bf16(af[mt], bfr[nt], acc[mt][nt], 0, 0, 0);
        }
        #pragma unroll
        for (int mt = 0; mt < 4; ++mt)
            for (int nt = 0; nt < 2; ++nt)
                for (int r = 0; r < 4; ++r) {
                    int cg = mt * 16 + quad * 4 + r;
                    int ci = nt * 16 + col;
                    Sred[wv * 2048 + cg * 32 + ci] = acc[mt][nt][r];
                }
    } else {
        int gw = wv - 4;
        const unsigned short* tb = th + (size_t)(b * NCI) * HWN;
        floatx4 ga[2][2];
        #pragma unroll
        for (int m = 0; m < 2; ++m)
            for (int n = 0; n < 2; ++n)
                ga[m][n] = (floatx4){0.f, 0.f, 0.f, 0.f};
        for (int t = gw; t < 98; t += 4) {
            int k0 = t * 32;
            short8 a0 = *(const short8*)&tb[(size_t)col * HWN + k0 + quad * 8];
            short8 a1 = *(const short8*)&tb[(size_t)(16 + col) * HWN + k0 + quad * 8];
            ga[0][0] = __builtin_amdgcn_mfma_f32_16x16x32_bf16(a0, a0, ga[0][0], 0, 0, 0);
            ga[0][1] = __builtin_amdgcn_mfma_f32_16x16x32_bf16(a0, a1, ga[0][1], 0, 0, 0);
            ga[1][0] = __builtin_amdgcn_mfma_f32_16x16x32_bf16(a1, a0, ga[1][0], 0, 0, 0);
            ga[1][1] = __builtin_amdgcn_mfma_f32_16x16x32_bf16(a1, a1, ga[1][1], 0, 0, 0);
        }
        #pragma unroll
        for (int m = 0; m < 2; ++m)
            for (int n = 0; n < 2; ++n)
                for (int r = 0; r < 4; ++r)
                    Gred[gw * 1024 + (m * 16 + quad * 4 + r) * 32 + n * 16 + col] = ga[m][n][r];
    }
    __syncthreads();

    // reduce S -> Sg global (bf16) + Sf (bf16-rounded f32) in place
    for (int idx = tid; idx < 2048; idx += 512) {
        float s = Sred[idx] + Sred[2048 + idx] + Sred[4096 + idx] + Sred[6144 + idx];
        int cg = idx >> 5, ci = idx & 31;
        unsigned short h = f2bf(s * (1.0f / NPP));
        Sg[(size_t)b * 2560 + cg * 40 + ci] = h;
        Sred[idx] = bf2f(h);
    }
    // reduce G in place (slice 0)
    for (int idx = tid; idx < 1024; idx += 512) {
        Gred[idx] = Gred[idx] + Gred[1024 + idx] + Gred[2048 + idx] + Gred[3072 + idx];
    }
    __syncthreads();

    // BN2 stats: sum = S.T1, sumsq = s^T G s ; 512 thr: cg x 8 ci-parts
    {
        int cg = tid & 63, part = tid >> 6;
        float sum = 0.f, sq = 0.f;
        #pragma unroll
        for (int i = 0; i < 4; ++i) {
            int ci = part * 4 + i;
            float sv = Sred[cg * 32 + ci];
            sum += sv * T1s[ci];
            float t = 0.f;
            #pragma unroll
            for (int cj = 0; cj < 32; ++cj)
                t += Gred[ci * 32 + cj] * Sred[cg * 32 + cj];
            sq += sv * t;
        }
        atomicAdd(&shs[cg], sum);
        atomicAdd(&shq[cg], sq);
    }
    __syncthreads();
    if (tid < 64) {
        atomicAdd(&bn2acc[tid], shs[tid]);
        atomicAdd(&bn2acc[64 + tid], shq[tid]);
    }
}

// ---------------- kernel 4: recompute y-tile + BN2+ReLU + conv1x1(z) + residual ----------------
// grid (49,B,2); 256 thr. M=64 hw x N=128 co-half, K=64; y recomputed from th & Sg.
__global__ __launch_bounds__(256) void k_convz(const unsigned short* __restrict__ th,
                                               const unsigned short* __restrict__ Sg,
                                               const unsigned short* __restrict__ wzb,
                                               const float* __restrict__ bn2acc,
                                               const float* __restrict__ gamma,
                                               const float* __restrict__ beta,
                                               const float* __restrict__ b_z,
                                               const float* __restrict__ x,
                                               float* __restrict__ out) {
    int b = blockIdx.y;
    int hw0 = blockIdx.x * 64;
    int coh = blockIdx.z * 128;
    int tid = threadIdx.x;
    int wv = tid >> 6, ln = tid & 63;
    int col = ln & 15, quad = ln >> 4;

    __shared__ unsigned short Wl[128 * 72];  // co-half weight tile
    __shared__ unsigned short TS[5120];      // Tt[64*40] + St[64*40]; Yt[64*72] overlays later
    __shared__ float ab2_s[128];
    unsigned short* Tt = TS;
    unsigned short* St = TS + 2560;
    unsigned short* Yt = TS;

    // W DMA: 18 chunks of 1 KB from pre-swizzled padded image
    for (int j = wv; j < 18; j += 4) {
        const unsigned short* gp = wzb + coh * 72 + j * 512 + ln * 8;
        __builtin_amdgcn_global_load_lds(
            (const __attribute__((address_space(1))) unsigned int*)gp,
            (__attribute__((address_space(3))) unsigned int*)&Wl[j * 512],
            16, 0, 0);
    }
    if (tid < 64) {   // BN2 finalize
        const float inv = 1.0f / (BB * HWN);
        float mean = bn2acc[tid] * inv;
        float var  = bn2acc[64 + tid] * inv - mean * mean;
        float a = gamma[tid] * rsqrtf(var + 1e-5f);
        ab2_s[tid] = a;
        ab2_s[64 + tid] = beta[tid] - mean * a;
    }
    {   // stage St flat (bf16 S, pre-scaled)
        const unsigned int* sgw = (const unsigned int*)(Sg + (size_t)b * 2560);
        unsigned int* stw = (unsigned int*)St;
        for (int i = tid; i < 1280; i += 256) stw[i] = sgw[i];
    }
    {   // stage theta transposed: Tt[hw][ci]
        int p2 = tid & 15, hwq = tid >> 4;
        int c0 = 2 * p2;
        const unsigned short* tb = th + (size_t)(b * NCI) * HWN + hw0 + hwq * 4;
        ushort4 v0 = *(const ushort4*)(tb + (size_t)c0 * HWN);
        ushort4 v1 = *(const ushort4*)(tb + (size_t)(c0 + 1) * HWN);
        unsigned int* tw = (unsigned int*)Tt;
        tw[(hwq * 4 + 0) * 20 + p2] = (unsigned)v0.x | ((unsigned)v1.x << 16);
        tw[(hwq * 4 + 1) * 20 + p2] = (unsigned)v0.y | ((unsigned)v1.y << 16);
        tw[(hwq * 4 + 2) * 20 + p2] = (unsigned)v0.z | ((unsigned)v1.z << 16);
        tw[(hwq * 4 + 3) * 20 + p2] = (unsigned)v0.w | ((unsigned)v1.w << 16);
    }
    __syncthreads();

    // recompute y tile: y[hw][cg] (verified k_y pattern)
    short8 afy = *(const short8*)&Tt[(wv * 16 + col) * 40 + quad * 8];
    floatx4 yacc[4];
    #pragma unroll
    for (int nt = 0; nt < 4; ++nt) {
        short8 bf = *(const short8*)&St[(nt * 16 + col) * 40 + quad * 8];
        floatx4 z = (floatx4){0.f, 0.f, 0.f, 0.f};
        yacc[nt] = __builtin_amdgcn_mfma_f32_16x16x32_bf16(afy, bf, z, 0, 0, 0);
    }
    __syncthreads();   // all Tt/St reads done before Yt overlay

    // BN2+ReLU + scatter to Yt[hw][cg]
    #pragma unroll
    for (int nt = 0; nt < 4; ++nt) {
        int cg = nt * 16 + col;
        float a = ab2_s[cg], d = ab2_s[64 + cg];
        #pragma unroll
        for (int r = 0; r < 4; ++r) {
            int hwl = wv * 16 + quad * 4 + r;
            Yt[hwl * 72 + cg] = f2bf(fmaxf(fmaf(a, yacc[nt][r], d), 0.f));
        }
    }
    __syncthreads();

    floatx4 acc[8];
    #pragma unroll
    for (int nt = 0; nt < 8; ++nt) acc[nt] = (floatx4){0.f, 0.f, 0.f, 0.f};

    #pragma unroll
    for (int kk = 0; kk < 2; ++kk) {
        short8 afm = *(const short8*)&Yt[(wv * 16 + col) * 72 + kk * 32 + quad * 8];
        #pragma unroll
        for (int nt = 0; nt < 8; ++nt) {
            short8 bf = *(const short8*)&Wl[(nt * 16 + col) * 72 + kk * 32 + quad * 8];
            acc[nt] = __builtin_amdgcn_mfma_f32_16x16x32_bf16(afm, bf, acc[nt], 0, 0, 0);
        }
    }

    #pragma unroll
    for (int nt = 0; nt < 8; ++nt) {
        int co = coh + nt * 16 + col;
        size_t base = ((size_t)(b * CC + co)) * HWN + hw0 + wv * 16 + quad * 4;
        float4 xv = *(const float4*)&x[base];
        float bz = b_z[co];
        float4 r = make_float4(acc[nt][0] + bz + xv.x, acc[nt][1] + bz + xv.y,
                               acc[nt][2] + bz + xv.z, acc[nt][3] + bz + xv.w);
        *(float4*)&out[base] = r;
    }
}

extern "C" void kernel_launch(void* const* d_in, const int* in_sizes, int n_in,
                              void* d_out, int out_size, void* d_ws, size_t ws_size,
                              hipStream_t stream) {
    (void)in_sizes; (void)n_in; (void)out_size; (void)ws_size;
    const float* x   = (const float*)d_in[0];
    const float* g1  = (const float*)d_in[1];
    const float* b1  = (const float*)d_in[2];
    const float* w_g = (const float*)d_in[3];
    const float* b_g = (const float*)d_in[4];
    const float* w_t = (const float*)d_in[5];
    const float* b_t = (const float*)d_in[6];
    const float* w_p = (const float*)d_in[7];
    const float* b_p = (const float*)d_in[8];
    const float* g2  = (const float*)d_in[9];
    const float* b2  = (const float*)d_in[10];
    const float* w_z = (const float*)d_in[11];
    const float* b_z = (const float*)d_in[12];
    float* out = (float*)d_out;

    float* ws     = (float*)d_ws;
    float* bn1acc = ws;                                       // 512
    float* bn2acc = ws + 512;                                 // 128
    float* T1g    = ws + 640;                                 // 512
    unsigned short* wcat = (unsigned short*)(ws + 1152);      // 32768 shorts
    unsigned short* wzb  = (unsigned short*)(ws + 17536);     // 18432 shorts
    unsigned short* th   = (unsigned short*)(ws + 26752);     // 1605632 shorts
    unsigned short* pool = (unsigned short*)(ws + 829568);    // 1228800 shorts
    unsigned short* Sg   = (unsigned short*)(ws + 1443968);   // 40960 shorts

    k_prep  <<<dim3(128),        dim3(256), 0, stream>>>(w_t, w_p, w_g, w_z, wcat, wzb, pool, ws);
    k_bn1a  <<<dim3(BB * CC),    dim3(256), 0, stream>>>(x, bn1acc);
    k_conv1 <<<dim3(28, BB),     dim3(256), 0, stream>>>(x, wcat, bn1acc, g1, b1, b_g, b_t, b_p, th, pool, T1g);
    k_sgemm <<<dim3(BB),         dim3(512), 0, stream>>>(pool, th, T1g, Sg, bn2acc);
    k_convz <<<dim3(49, BB, 2),  dim3(256), 0, stream>>>(th, Sg, wzb, bn2acc, g2, b2, b_z, x, out);
}